// Round 7
// baseline (522.355 us; speedup 1.0000x reference)
//
#include <hip/hip_runtime.h>

typedef _Float16 half8 __attribute__((ext_vector_type(8)));
typedef float f32x16 __attribute__((ext_vector_type(16)));

__device__ __forceinline__ unsigned short f2h(float f) {
    _Float16 h = (_Float16)f;
    return __builtin_bit_cast(unsigned short, h);
}
__device__ __forceinline__ float h2f(unsigned short u) {
    return (float)__builtin_bit_cast(_Float16, u);
}

// async global->LDS, 16 B per lane; LDS dest linear (base + lane*16)
__device__ __forceinline__ void lds_load16(const uint4* g, uint4* l) {
    __builtin_amdgcn_global_load_lds(
        (const __attribute__((address_space(1))) unsigned int*)g,
        (__attribute__((address_space(3))) unsigned int*)l, 16, 0, 0);
}

// integral image layout: plane stride, row stride, +3 element offset so that
// element x=1+4k is 16B-aligned (float4 stores in rowprep)
#define IIROW 260
#define IIPLANE 66824  // 257*260 + pad

// ---- weight transform: OIHW fp32 -> [ck][pos][oct(ci/8)][co][ci&7] fp16 ----
__global__ void wprep_k(const float* __restrict__ src, unsigned short* __restrict__ dst,
                        int Cout, int Cin, int total)
{
    int t = blockIdx.x * 256 + threadIdx.x;
    if (t >= total) return;
    int j = t & 7; int r = t >> 3;
    int co = r % Cout; r /= Cout;
    int oct = r & 3; r >>= 2;
    int pos = r % 9; int ck = r / 9;
    int ci = ck * 32 + oct * 8 + j;
    dst[t] = f2h(src[((size_t)co * Cin + ci) * 9 + pos]);
}

// ---- fc weight transpose: fcw[f][k] -> fcwT[k][f] (49 x 512) ----
__global__ void fct_k(const float* __restrict__ src, float* __restrict__ dst)
{
    int t = blockIdx.x * 256 + threadIdx.x;
    if (t >= 49 * 512) return;
    int k = t >> 9, f = t & 511;
    dst[t] = src[f * 49 + k];
}

// ---- MFMA 32x32x16 conv3x3 SAME, NHWC fp16, fp32 accum ----
// Block 256 thr = 4 waves; tile 64 x TH px; BM out-channels (32 or 64).
// Wave: NMt (=BM/32) co-tiles x NNt (=TH/2) px-groups of 32.
// LDS: input [oct(4)][TH+2][66] granules(16B), weights [pos*4+oct][co].
template<int BM, int TH, int LW, int UP, int C1G, int C2G, int COUT>
__global__ __launch_bounds__(256, 2) void convm3_k(
    const uint4* __restrict__ in1, const uint4* __restrict__ in2,
    const uint4* __restrict__ wt, const float* __restrict__ bias,
    unsigned short* __restrict__ out, int relu, const uint4* __restrict__ zp)
{
    constexpr int NMt = BM / 32;
    constexpr int NNt = TH / 2;
    constexpr int Wf = 1 << LW, Hf = Wf;
    constexpr int WC = 66, HR = TH + 2;
    constexpr int IN_GR = 4 * HR * WC;
    constexpr int WT_GR = 36 * BM;
    constexpr int NI = (IN_GR + 255) / 256;
    constexpr int NW = (WT_GR + 255) / 256;
    constexpr int NCK = (C1G + C2G) / 4;
    constexpr int sH1 = UP ? (Hf >> 1) : Hf;
    constexpr int sW1 = UP ? (Wf >> 1) : Wf;
    constexpr int ng = COUT / BM;
    constexpr int LB = (BM == 32) ? 5 : 6;
    __shared__ uint4 smem[IN_GR + WT_GR];

    const int tid = threadIdx.x;
    const int lane = tid & 63, wv = tid >> 6;
    const int b = blockIdx.z / ng, cg = blockIdx.z % ng;
    const int x0 = blockIdx.x * 64, y0 = blockIdx.y * TH;

    // per-slot global pointers for input staging (advance 4 granules/chunk)
    const uint4* gp[NI];
#pragma unroll
    for (int it = 0; it < NI; ++it) {
        const int i = tid + it * 256;
        const int oct = i / (HR * WC);
        const int rem = i - oct * (HR * WC);
        const int row = rem / WC, col = rem - row * WC;
        const int gy = y0 + row - 1, gx = x0 + col - 1;
        const int sy = UP ? (gy >> 1) : gy, sx = UP ? (gx >> 1) : gx;
        const bool ok = (i < IN_GR) && ((unsigned)gy < (unsigned)Hf) &&
                        ((unsigned)gx < (unsigned)Wf);
        gp[it] = ok ? (in1 + (size_t)((b * sH1 + sy) * sW1 + sx) * C1G + oct)
                    : (zp + lane);
    }
    const uint4* wck = wt + (size_t)cg * BM;

    f32x16 acc[NMt][NNt];
#pragma unroll
    for (int m = 0; m < NMt; ++m)
#pragma unroll
        for (int n = 0; n < NNt; ++n)
#pragma unroll
            for (int q = 0; q < 16; ++q) acc[m][n][q] = 0.f;

    const int l31 = lane & 31, l5 = lane >> 5;

    for (int ck = 0; ck < NCK; ++ck) {
        if (ck) __syncthreads();
        if constexpr (C2G > 0) {
            if (ck * 4 == C1G) {  // concat: switch staging source to in2
#pragma unroll
                for (int it = 0; it < NI; ++it) {
                    const int i = tid + it * 256;
                    const int oct = i / (HR * WC);
                    const int rem = i - oct * (HR * WC);
                    const int row = rem / WC, col = rem - row * WC;
                    const int gy = y0 + row - 1, gx = x0 + col - 1;
                    const int sy = UP ? (gy >> 1) : gy, sx = UP ? (gx >> 1) : gx;
                    const bool ok = (i < IN_GR) && ((unsigned)gy < (unsigned)Hf) &&
                                    ((unsigned)gx < (unsigned)Wf);
                    gp[it] = ok ? (in2 + (size_t)((b * sH1 + sy) * sW1 + sx) * C2G + oct)
                                : (zp + lane);
                }
            }
        }
#pragma unroll
        for (int it = 0; it < NI; ++it) {
            const int i = tid + it * 256;
            if (i < IN_GR) lds_load16(gp[it], &smem[i]);
            gp[it] += 4;
        }
#pragma unroll
        for (int it = 0; it < NW; ++it) {
            const int i = tid + it * 256;
            if (i < WT_GR)
                lds_load16(wck + (i >> LB) * COUT + (i & (BM - 1)), &smem[IN_GR + i]);
        }
        wck += 36 * COUT;
        __syncthreads();

        const half8* sB = (const half8*)smem;
        const half8* sA = (const half8*)(smem + IN_GR);
#pragma unroll
        for (int pos = 0; pos < 9; ++pos) {
            const int dr = pos / 3, dc = pos - dr * 3;
            half8 af[NMt][2], bf[NNt][2];
#pragma unroll
            for (int m = 0; m < NMt; ++m)
#pragma unroll
                for (int s = 0; s < 2; ++s)
                    af[m][s] = sA[(pos * 4 + 2 * s + l5) * BM + m * 32 + l31];
#pragma unroll
            for (int n = 0; n < NNt; ++n) {
                const int pb = wv * (NNt * 32) + n * 32;
                const int rn = (pb >> 6) + dr;
                const int xn = (pb & 63) + dc;
#pragma unroll
                for (int s = 0; s < 2; ++s)
                    bf[n][s] = sB[(2 * s + l5) * (HR * WC) + rn * WC + xn + l31];
            }
#pragma unroll
            for (int m = 0; m < NMt; ++m)
#pragma unroll
                for (int n = 0; n < NNt; ++n) {
                    acc[m][n] = __builtin_amdgcn_mfma_f32_32x32x16_f16(af[m][0], bf[n][0], acc[m][n], 0, 0, 0);
                    acc[m][n] = __builtin_amdgcn_mfma_f32_32x32x16_f16(af[m][1], bf[n][1], acc[m][n], 0, 0, 0);
                }
        }
    }

    // epilogue: C/D 32x32 layout: col(px)=lane&31, row(co)=(reg&3)+8*(reg>>2)+4*(lane>>5)
#pragma unroll
    for (int m = 0; m < NMt; ++m)
#pragma unroll
        for (int n = 0; n < NNt; ++n) {
            const int pix = wv * (NNt * 32) + n * 32 + l31;
            const int y = y0 + (pix >> 6), x = x0 + (pix & 63);
            unsigned short* op = out + (((size_t)b * Hf + y) * Wf + x) * COUT
                                 + cg * BM + m * 32 + l5 * 4;
#pragma unroll
            for (int rq = 0; rq < 4; ++rq) {
                const float4 bs = *(const float4*)(bias + cg * BM + m * 32 + l5 * 4 + rq * 8);
                float v0 = acc[m][n][rq * 4 + 0] + bs.x;
                float v1 = acc[m][n][rq * 4 + 1] + bs.y;
                float v2 = acc[m][n][rq * 4 + 2] + bs.z;
                float v3 = acc[m][n][rq * 4 + 3] + bs.w;
                if (relu) {
                    v0 = fmaxf(v0, 0.f); v1 = fmaxf(v1, 0.f);
                    v2 = fmaxf(v2, 0.f); v3 = fmaxf(v3, 0.f);
                }
                uint2 pk;
                pk.x = (unsigned)f2h(v0) | ((unsigned)f2h(v1) << 16);
                pk.y = (unsigned)f2h(v2) | ((unsigned)f2h(v3) << 16);
                *(uint2*)(op + rq * 8) = pk;
            }
        }
}

// ---- first conv 3->32, fp32 direct, NCHW fp32 in -> NHWC fp16 out ----
__global__ __launch_bounds__(256) void conv0_k(
    const float* __restrict__ in, const float* __restrict__ w,
    const float* __restrict__ bias, unsigned short* __restrict__ out)
{
    __shared__ float s_in[3][18][18];
    const int tx = threadIdx.x, ty = threadIdx.y;
    const int tid = ty * 16 + tx;
    const int b = blockIdx.z >> 2;
    const int coBase = (blockIdx.z & 3) * 8;
    const int bx = blockIdx.x * 16, by = blockIdx.y * 16;

    for (int i = tid; i < 3 * 18 * 18; i += 256) {
        int cc = i / 324, r = i % 324;
        int ly = r / 18, lx = r % 18;
        int gy = by + ly - 1, gx = bx + lx - 1;
        float v = 0.f;
        if ((unsigned)gy < 256u && (unsigned)gx < 256u)
            v = in[(((size_t)(b * 3 + cc)) << 16) + (gy << 8) + gx];
        ((float*)s_in)[i] = v;
    }
    __syncthreads();
    float acc[8];
#pragma unroll
    for (int k = 0; k < 8; ++k) acc[k] = 0.f;
    for (int cc = 0; cc < 3; ++cc) {
        float v[9];
#pragma unroll
        for (int dh = 0; dh < 3; ++dh)
#pragma unroll
            for (int dw = 0; dw < 3; ++dw)
                v[dh * 3 + dw] = s_in[cc][ty + dh][tx + dw];
        const float* wp = w + ((size_t)coBase * 3 + cc) * 9;
#pragma unroll
        for (int k = 0; k < 8; ++k) {
            const float* wk = wp + (size_t)k * 27;
            float a = acc[k];
#pragma unroll
            for (int j = 0; j < 9; ++j) a = fmaf(v[j], wk[j], a);
            acc[k] = a;
        }
    }
    const int h = by + ty, ww = bx + tx;
    unsigned short* op = out + (((size_t)(b * 256 + h)) * 256 + ww) * 32 + coBase;
#pragma unroll
    for (int k = 0; k < 8; ++k)
        op[k] = f2h(fmaxf(acc[k] + bias[coBase + k], 0.f));
}

// ---- 2x2 maxpool stride 2, NHWC fp16, 8 ch per thread ----
__global__ void poolh_k(const uint4* __restrict__ in, uint4* __restrict__ out,
                        int Ho, int Wo, int C8, int total)
{
    int i = blockIdx.x * 256 + threadIdx.x;
    if (i >= total) return;
    int oct = i % C8; int p = i / C8;
    int x = p % Wo; p /= Wo;
    int y = p % Ho; int b = p / Ho;
    const int H = Ho * 2, W = Wo * 2;
    size_t g = (((size_t)b * H + 2 * y) * W + 2 * x) * C8 + oct;
    uint4 v00 = in[g], v01 = in[g + C8];
    uint4 v10 = in[g + (size_t)W * C8], v11 = in[g + (size_t)W * C8 + C8];
    const unsigned short* a0 = (const unsigned short*)&v00;
    const unsigned short* a1 = (const unsigned short*)&v01;
    const unsigned short* a2 = (const unsigned short*)&v10;
    const unsigned short* a3 = (const unsigned short*)&v11;
    uint4 res; unsigned short* rp = (unsigned short*)&res;
#pragma unroll
    for (int j = 0; j < 8; ++j)
        rp[j] = f2h(fmaxf(fmaxf(h2f(a0[j]), h2f(a1[j])), fmaxf(h2f(a2[j]), h2f(a3[j]))));
    out[(((size_t)b * Ho + y) * Wo + x) * C8 + oct] = res;
}

// ---- fused 1x1 conv (32->32) + row inclusive scan -> ii rows ----
// Scan: lane owns 4 px (b128 read), 1 wave-scan of lane sums (6 shfl), float4 store.
__global__ __launch_bounds__(256) void rowprep_k(
    const uint4* __restrict__ in, const float* __restrict__ w,
    const float* __restrict__ bias, float* __restrict__ ii)
{
    __shared__ float sw[1024];
    __shared__ float sb[32];
    __shared__ float sout[32][256];
    const int tid = threadIdx.x;
    const int lane = tid & 63, wv = tid >> 6;
    const int y = blockIdx.x, b = blockIdx.y;
    for (int i = tid; i < 1024; i += 256) sw[i] = w[i];
    if (tid < 32) sb[tid] = bias[tid];
    __syncthreads();

    float xv[32];
    const uint4* ip = in + (((size_t)b * 256 + y) * 256 + tid) * 4;
#pragma unroll
    for (int q = 0; q < 4; ++q) {
        uint4 g = ip[q];
        const unsigned short* gs = (const unsigned short*)&g;
#pragma unroll
        for (int j = 0; j < 8; ++j) xv[q * 8 + j] = h2f(gs[j]);
    }
#pragma unroll
    for (int co = 0; co < 32; ++co) {
        float a = sb[co];
#pragma unroll
        for (int ci = 0; ci < 32; ++ci) a = fmaf(xv[ci], sw[co * 32 + ci], a);
        sout[co][tid] = a;
    }
    __syncthreads();
    float* plane0 = ii + (size_t)(b * 32) * IIPLANE;
    if (y == 0) {  // zero the y=0 border row of every channel plane
        for (int i = tid; i < 32 * 257; i += 256) {
            int c = i / 257, xx = i % 257;
            plane0[(size_t)c * IIPLANE + xx + 3] = 0.f;
        }
    }
    // each wave scans 8 channels of this row
    for (int cc = 0; cc < 8; ++cc) {
        const int c = wv * 8 + cc;
        float* prow = plane0 + (size_t)c * IIPLANE + (size_t)(y + 1) * IIROW;
        float4 v = *(const float4*)&sout[c][lane * 4];
        float s0 = v.x, s1 = s0 + v.y, s2 = s1 + v.z, s3 = s2 + v.w;
        float t = s3;
#pragma unroll
        for (int off = 1; off < 64; off <<= 1) {
            float u = __shfl_up(t, off);
            if (lane >= off) t += u;
        }
        const float base = t - s3;  // exclusive prefix of lane sums
        float4 o;
        o.x = base + s0; o.y = base + s1; o.z = base + s2; o.w = base + s3;
        *(float4*)(prow + 4 + lane * 4) = o;  // elements x=1+4l..(+3), 16B aligned
        if (lane == 0) prow[3] = 0.f;         // x = 0
    }
}

// ---- segmented column scan: pass A (64-row segment column sums) ----
__global__ __launch_bounds__(256) void colA_k(const float* __restrict__ ii,
                                              float* __restrict__ S)
{
    const int p = blockIdx.x, s = blockIdx.y;  // s in 0..2
    const int x = threadIdx.x;
    const float* plane = ii + (size_t)p * IIPLANE;
    float acc = 0.f;
#pragma unroll 8
    for (int y = s * 64 + 1; y <= s * 64 + 64; ++y)
        acc += plane[(size_t)y * IIROW + x + 4];
    S[(p * 3 + s) * 256 + x] = acc;
}

// ---- segmented column scan: pass B (apply prefixes, in-place scan) ----
__global__ __launch_bounds__(256) void colB_k(float* __restrict__ ii,
                                              const float* __restrict__ S)
{
    const int p = blockIdx.x, s = blockIdx.y;  // s in 0..3
    const int x = threadIdx.x;
    float* plane = ii + (size_t)p * IIPLANE;
    float acc = 0.f;
    for (int t = 0; t < s; ++t) acc += S[(p * 3 + t) * 256 + x];
#pragma unroll 8
    for (int y = s * 64 + 1; y <= s * 64 + 64; ++y) {
        float* q = plane + (size_t)y * IIROW + x + 4;
        acc += *q;
        *q = acc;
    }
}

// ---- adaptive ROI pool via integral image -> pooled[b][n][49] ----
__global__ void pool_k(const float* __restrict__ ii, const int* __restrict__ rois,
                       float* __restrict__ pooled)
{
    int t = blockIdx.x * 256 + threadIdx.x;
    int k = t % 49; int nb = t / 49;
    int n = nb % 1056; int b = nb / 1056;
    int ki = k / 7, kj = k % 7;
    int x1, y1, x2, y2, c;
    if (n < 32) {
        x1 = 0; y1 = 0; x2 = 256; y2 = 256; c = n;
    } else {
        int r = (n - 32) >> 5;
        c = (n - 32) & 31;
        x1 = rois[r * 4 + 0]; y1 = rois[r * 4 + 1];
        x2 = rois[r * 4 + 2]; y2 = rois[r * 4 + 3];
    }
    const int h = y2 - y1, w = x2 - x1;
    const int sy = y1 + (ki * h) / 7, ey = y1 + ((ki + 1) * h + 6) / 7;
    const int sx = x1 + (kj * w) / 7, ex = x1 + ((kj + 1) * w + 6) / 7;
    const float* pl = ii + (size_t)(b * 32 + c) * IIPLANE + 3;
    float s = pl[ey * IIROW + ex] - pl[sy * IIROW + ex]
            - pl[ey * IIROW + sx] + pl[sy * IIROW + sx];
    pooled[t] = s / (float)((ey - sy) * (ex - sx));
}

// ---- FC: out[b,n,f] = pooled[b,n,:] . fcwT[:,f] + fcb[f] ----
__global__ __launch_bounds__(512) void fc_k(
    const float* __restrict__ pooled, const float* __restrict__ fcwT,
    const float* __restrict__ fcb, float* __restrict__ out)
{
    const int nt = blockIdx.x, b = blockIdx.y;
    const int f = threadIdx.x;
    float wr[49];
#pragma unroll
    for (int k = 0; k < 49; ++k) wr[k] = fcwT[k * 512 + f];
    const float base = fcb[f];
    const float* pr = pooled + ((size_t)b * 1056 + nt * 16) * 49;
    float* op = out + (((size_t)b * 1056 + nt * 16)) * 512 + f;
#pragma unroll
    for (int j = 0; j < 16; ++j) {
        float a = base;
#pragma unroll
        for (int k = 0; k < 49; ++k)
            a = fmaf(pr[j * 49 + k], wr[k], a);
        op[(size_t)j * 512] = a;
    }
}

extern "C" void kernel_launch(void* const* d_in, const int* in_sizes, int n_in,
                              void* d_out, int out_size, void* d_ws, size_t ws_size,
                              hipStream_t stream)
{
    const float* x    = (const float*)d_in[0];
    const int*   rois = (const int*)d_in[1];
    const float* e1w1 = (const float*)d_in[2];
    const float* e1b1 = (const float*)d_in[3];
    const float* e1w2 = (const float*)d_in[4];
    const float* e1b2 = (const float*)d_in[5];
    const float* e2w1 = (const float*)d_in[6];
    const float* e2b1 = (const float*)d_in[7];
    const float* e2w2 = (const float*)d_in[8];
    const float* e2b2 = (const float*)d_in[9];
    const float* bw1  = (const float*)d_in[10];
    const float* bb1  = (const float*)d_in[11];
    const float* bw2  = (const float*)d_in[12];
    const float* bb2  = (const float*)d_in[13];
    const float* u2w  = (const float*)d_in[14];
    const float* u2b  = (const float*)d_in[15];
    const float* d2w1 = (const float*)d_in[16];
    const float* d2b1 = (const float*)d_in[17];
    const float* d2w2 = (const float*)d_in[18];
    const float* d2b2 = (const float*)d_in[19];
    const float* u1w  = (const float*)d_in[20];
    const float* u1b  = (const float*)d_in[21];
    const float* d1w1 = (const float*)d_in[22];
    const float* d1b1 = (const float*)d_in[23];
    const float* d1w2 = (const float*)d_in[24];
    const float* d1b2 = (const float*)d_in[25];
    const float* fw   = (const float*)d_in[26];
    const float* fb   = (const float*)d_in[27];
    const float* fcw  = (const float*)d_in[28];
    const float* fcb  = (const float*)d_in[29];

    // ---- workspace: WT(4MB) A(33.5) D(16.8) E(16.8) B(33.5) C(8.4) F(68.5)
    char* wsb = (char*)d_ws;
    char* WT = wsb;
    char* A  = wsb + 4194304;
    char* D  = A + 33554432;
    char* E  = D + 16777216;
    char* Bb = E + 16777216;
    char* C  = Bb + 33554432;
    char* F  = C + 8388608;
    float* ii     = (float*)F;                     // 256 planes * IIPLANE * 4B = 68.4 MB
    float* fcwT   = (float*)(WT + 1048576);
    uint4* zp     = (uint4*)(WT + 4194304 - 8192);
    float* pooled = (float*)C;
    float* Sbuf   = (float*)(C + 2097152);
    hipMemsetAsync(zp, 0, 8192, stream);

    // ---- weight transforms ----
    const float* wsrc[11] = {e1w2, e2w1, e2w2, bw1, bw2, u2w, d2w1, d2w2, u1w, d1w1, d1w2};
    const int wco[11] = {32, 64, 64, 128, 128, 64, 64, 64, 32, 32, 32};
    const int wci[11] = {32, 32, 64, 64, 128, 128, 128, 64, 64, 64, 32};
    size_t woff[11]; size_t o = 0;
    for (int i = 0; i < 11; ++i) { woff[i] = o; o += (size_t)wco[i] * wci[i] * 18; }
    for (int i = 0; i < 11; ++i) {
        int total = wco[i] * wci[i] * 9;
        hipLaunchKernelGGL(wprep_k, dim3((total + 255) / 256), dim3(256), 0, stream,
                           wsrc[i], (unsigned short*)(WT + woff[i]), wco[i], wci[i], total);
    }
    hipLaunchKernelGGL(fct_k, dim3((49 * 512 + 255) / 256), dim3(256), 0, stream, fcw, fcwT);
    auto WP = [&](int i) { return (const uint4*)(WT + woff[i]); };

    // encoder
    hipLaunchKernelGGL(conv0_k, dim3(16, 16, 32), dim3(16, 16), 0, stream,
                       x, e1w1, e1b1, (unsigned short*)A);               // e1a -> A
    hipLaunchKernelGGL((convm3_k<32,8,8,0,4,0,32>), dim3(4,32,8), dim3(256), 0, stream,
        (const uint4*)A, nullptr, WP(0), e1b2, (unsigned short*)Bb, 1, zp);   // e1 -> B
    {
        int N = 8 * 128 * 128 * 4;
        hipLaunchKernelGGL(poolh_k, dim3((N + 255) / 256), dim3(256), 0, stream,
                           (const uint4*)Bb, (uint4*)C, 128, 128, 4, N);      // p1 -> C
    }
    hipLaunchKernelGGL((convm3_k<64,8,7,0,4,0,64>), dim3(2,16,8), dim3(256), 0, stream,
        (const uint4*)C, nullptr, WP(1), e2b1, (unsigned short*)A, 1, zp);    // e2a -> A
    hipLaunchKernelGGL((convm3_k<64,8,7,0,8,0,64>), dim3(2,16,8), dim3(256), 0, stream,
        (const uint4*)A, nullptr, WP(2), e2b2, (unsigned short*)D, 1, zp);    // e2 -> D
    {
        int N = 8 * 64 * 64 * 8;
        hipLaunchKernelGGL(poolh_k, dim3((N + 255) / 256), dim3(256), 0, stream,
                           (const uint4*)D, (uint4*)C, 64, 64, 8, N);         // p2 -> C
    }
    // bottleneck
    hipLaunchKernelGGL((convm3_k<64,4,6,0,8,0,128>), dim3(1,16,16), dim3(256), 0, stream,
        (const uint4*)C, nullptr, WP(3), bb1, (unsigned short*)E, 1, zp);     // b1 -> E
    hipLaunchKernelGGL((convm3_k<64,4,6,0,16,0,128>), dim3(1,16,16), dim3(256), 0, stream,
        (const uint4*)E, nullptr, WP(4), bb2, (unsigned short*)A, 1, zp);     // b2 -> A
    // decoder level 2
    hipLaunchKernelGGL((convm3_k<64,8,7,1,16,0,64>), dim3(2,16,8), dim3(256), 0, stream,
        (const uint4*)A, nullptr, WP(5), u2b, (unsigned short*)E, 1, zp);     // u2 -> E
    hipLaunchKernelGGL((convm3_k<64,8,7,0,8,8,64>), dim3(2,16,8), dim3(256), 0, stream,
        (const uint4*)E, (const uint4*)D, WP(6), d2b1, (unsigned short*)A, 1, zp); // d2a -> A
    hipLaunchKernelGGL((convm3_k<64,8,7,0,8,0,64>), dim3(2,16,8), dim3(256), 0, stream,
        (const uint4*)A, nullptr, WP(7), d2b2, (unsigned short*)D, 1, zp);    // d2 -> D
    // decoder level 1
    hipLaunchKernelGGL((convm3_k<32,8,8,1,8,0,32>), dim3(4,32,8), dim3(256), 0, stream,
        (const uint4*)D, nullptr, WP(8), u1b, (unsigned short*)A, 1, zp);     // u1 -> A
    hipLaunchKernelGGL((convm3_k<32,8,8,0,4,4,32>), dim3(4,32,8), dim3(256), 0, stream,
        (const uint4*)A, (const uint4*)Bb, WP(9), d1b1, (unsigned short*)D, 1, zp); // d1a -> D+E
    hipLaunchKernelGGL((convm3_k<32,8,8,0,4,0,32>), dim3(4,32,8), dim3(256), 0, stream,
        (const uint4*)D, nullptr, WP(10), d1b2, (unsigned short*)Bb, 1, zp);  // d1 -> B
    // fused 1x1 conv + row scan -> ii rows
    hipLaunchKernelGGL(rowprep_k, dim3(256, 8), dim3(256), 0, stream,
                       (const uint4*)Bb, fw, fb, ii);
    // segmented column scan
    hipLaunchKernelGGL(colA_k, dim3(256, 3), dim3(256), 0, stream, ii, Sbuf);
    hipLaunchKernelGGL(colB_k, dim3(256, 4), dim3(256), 0, stream, ii, Sbuf);
    // ROI pool + FC
    hipLaunchKernelGGL(pool_k, dim3(8 * 1056 * 49 / 256), dim3(256), 0, stream,
                       ii, rois, pooled);
    hipLaunchKernelGGL(fc_k, dim3(66, 8), dim3(512), 0, stream,
                       pooled, fcwT, fcb, (float*)d_out);
}

// Round 8
// 422.070 us; speedup vs baseline: 1.2376x; 1.2376x over previous
//
#include <hip/hip_runtime.h>

typedef _Float16 half8 __attribute__((ext_vector_type(8)));
typedef float f32x4 __attribute__((ext_vector_type(4)));
typedef float f32x16 __attribute__((ext_vector_type(16)));

__device__ __forceinline__ unsigned short f2h(float f) {
    _Float16 h = (_Float16)f;
    return __builtin_bit_cast(unsigned short, h);
}
__device__ __forceinline__ float h2f(unsigned short u) {
    return (float)__builtin_bit_cast(_Float16, u);
}

// async global->LDS, 16 B per lane; LDS dest linear (base + lane*16)
__device__ __forceinline__ void lds_load16(const uint4* g, uint4* l) {
    __builtin_amdgcn_global_load_lds(
        (const __attribute__((address_space(1))) unsigned int*)g,
        (__attribute__((address_space(3))) unsigned int*)l, 16, 0, 0);
}

// integral image layout: +3 offset so x=1+4k is 16B-aligned
#define IIROW 260
#define IIPLANE 66824

// ---- weight transform: OIHW fp32 -> [ck][pos][oct(ci/8)][co][ci&7] fp16 ----
__global__ void wprep_k(const float* __restrict__ src, unsigned short* __restrict__ dst,
                        int Cout, int Cin, int total)
{
    int t = blockIdx.x * 256 + threadIdx.x;
    if (t >= total) return;
    int j = t & 7; int r = t >> 3;
    int co = r % Cout; r /= Cout;
    int oct = r & 3; r >>= 2;
    int pos = r % 9; int ck = r / 9;
    int ci = ck * 32 + oct * 8 + j;
    dst[t] = f2h(src[((size_t)co * Cin + ci) * 9 + pos]);
}

// ---- 1x1 weight transform: fw[co][ci] fp32 -> [koct(4)][co(32)][ci&7] fp16 ----
__global__ void w1prep_k(const float* __restrict__ src, unsigned short* __restrict__ dst)
{
    int t = blockIdx.x * 256 + threadIdx.x;
    if (t >= 4096) return;
    int j = t & 7, co = (t >> 3) & 31, koct = t >> 8;
    dst[t] = f2h(src[co * 32 + koct * 8 + j]);
}

// ---- fc weight transpose: fcw[f][k] -> fcwT[k][f] (49 x 512) ----
__global__ void fct_k(const float* __restrict__ src, float* __restrict__ dst)
{
    int t = blockIdx.x * 256 + threadIdx.x;
    if (t >= 49 * 512) return;
    int k = t >> 9, f = t & 511;
    dst[t] = src[f * 49 + k];
}

// ---- MFMA conv3x3 SAME, NHWC fp16, fp32 accum; 2D tiles (round-6 version) ----
template<int BM, int TW, int TH, int LW, int UP>
__global__ __launch_bounds__(256, 2) void convm2_k(
    const uint4* __restrict__ in1, int C1g,
    const uint4* __restrict__ in2, int C2g,
    const uint4* __restrict__ wt,
    const float* __restrict__ bias,
    unsigned short* __restrict__ out,
    int Cout, int relu, const uint4* __restrict__ zp)
{
    constexpr int NM = BM / 16;
    constexpr int NN = (TW * TH) / 64;
    constexpr int Wf = 1 << LW, Hf = Wf;
    constexpr int WC = TW + 2, HR = TH + 2;
    constexpr int IN_GR = 4 * HR * WC;
    constexpr int LTW = (TW == 64) ? 6 : ((TW == 32) ? 5 : 7);
    constexpr int sH = UP ? (Hf >> 1) : Hf;
    constexpr int sW = UP ? (Wf >> 1) : Wf;
    __shared__ uint4 smem[IN_GR + 36 * BM];

    const int tid = threadIdx.x;
    const int lane = tid & 63, wv = tid >> 6;
    const int ng = Cout / BM;
    const int b = blockIdx.z / ng, cg = blockIdx.z % ng;
    const int x0 = blockIdx.x * TW, y0 = blockIdx.y * TH;
    const int NCK = (C1g + C2g) / 4;

    f32x4 acc[NM][NN];
#pragma unroll
    for (int m = 0; m < NM; ++m)
#pragma unroll
        for (int n = 0; n < NN; ++n) acc[m][n] = (f32x4){0.f, 0.f, 0.f, 0.f};

    const int l15 = lane & 15, l4 = lane >> 4;
    const int laneB = l4 * HR * WC + l15;
    const int laneA = l4 * BM + l15;

    for (int ck = 0; ck < NCK; ++ck) {
        if (ck) __syncthreads();
        {
            const uint4* src; int cg0, srcCg;
            if (ck * 4 < C1g) { src = in1; cg0 = ck * 4; srcCg = C1g; }
            else              { src = in2; cg0 = ck * 4 - C1g; srcCg = C2g; }
            for (int i = tid; i < IN_GR; i += 256) {
                int oct = i / (HR * WC);
                int rem = i - oct * (HR * WC);
                int row = rem / WC;
                int col = rem - row * WC;
                int gy = y0 + row - 1, gx = x0 + col - 1;
                int sy = UP ? (gy >> 1) : gy, sx = UP ? (gx >> 1) : gx;
                const uint4* ga = ((unsigned)gy < (unsigned)Hf && (unsigned)gx < (unsigned)Wf)
                    ? src + ((((size_t)b * sH + sy) * sW + sx) * srcCg + cg0 + oct)
                    : zp + (i & 63);
                lds_load16(ga, &smem[i]);
            }
        }
        {
            const uint4* wck = wt + (size_t)ck * 36 * Cout + (size_t)cg * BM;
            for (int i = tid; i < 36 * BM; i += 256) {
                int seg = i / BM, col = i - seg * BM;
                lds_load16(wck + seg * Cout + col, &smem[IN_GR + i]);
            }
        }
        __syncthreads();
        const half8* sB = (const half8*)smem;
        const half8* sA = (const half8*)(smem + IN_GR);
#pragma unroll
        for (int pos = 0; pos < 9; ++pos) {
            const int dr = pos / 3, dc = pos - dr * 3;
            half8 af[NM], bfr[NN];
#pragma unroll
            for (int m = 0; m < NM; ++m)
                af[m] = sA[pos * 4 * BM + m * 16 + laneA];
#pragma unroll
            for (int n = 0; n < NN; ++n) {
                const int pb = wv * (NN * 16) + n * 16;
                const int rn = (pb >> LTW) + dr;
                const int xn = (pb & (TW - 1)) + dc;
                bfr[n] = sB[rn * WC + xn + laneB];
            }
#pragma unroll
            for (int m = 0; m < NM; ++m)
#pragma unroll
                for (int n = 0; n < NN; ++n)
                    acc[m][n] = __builtin_amdgcn_mfma_f32_16x16x32_f16(af[m], bfr[n], acc[m][n], 0, 0, 0);
        }
    }

#pragma unroll
    for (int m = 0; m < NM; ++m) {
        const int co0 = cg * BM + m * 16 + l4 * 4;
        const float4 bs = *(const float4*)(bias + co0);
#pragma unroll
        for (int n = 0; n < NN; ++n) {
            const int pix = wv * (NN * 16) + n * 16 + l15;
            const int y = y0 + (pix >> LTW), x = x0 + (pix & (TW - 1));
            float v0 = acc[m][n][0] + bs.x;
            float v1 = acc[m][n][1] + bs.y;
            float v2 = acc[m][n][2] + bs.z;
            float v3 = acc[m][n][3] + bs.w;
            if (relu) {
                v0 = fmaxf(v0, 0.f); v1 = fmaxf(v1, 0.f);
                v2 = fmaxf(v2, 0.f); v3 = fmaxf(v3, 0.f);
            }
            uint2 pk;
            pk.x = (unsigned)f2h(v0) | ((unsigned)f2h(v1) << 16);
            pk.y = (unsigned)f2h(v2) | ((unsigned)f2h(v3) << 16);
            *(uint2*)(out + (((size_t)b * Hf + y) * Wf + x) * Cout + co0) = pk;
        }
    }
}

// ---- first conv 3->32, fp32 direct, NCHW fp32 in -> NHWC fp16 out ----
__global__ __launch_bounds__(256) void conv0_k(
    const float* __restrict__ in, const float* __restrict__ w,
    const float* __restrict__ bias, unsigned short* __restrict__ out)
{
    __shared__ float s_in[3][18][18];
    const int tx = threadIdx.x, ty = threadIdx.y;
    const int tid = ty * 16 + tx;
    const int b = blockIdx.z >> 2;
    const int coBase = (blockIdx.z & 3) * 8;
    const int bx = blockIdx.x * 16, by = blockIdx.y * 16;

    for (int i = tid; i < 3 * 18 * 18; i += 256) {
        int cc = i / 324, r = i % 324;
        int ly = r / 18, lx = r % 18;
        int gy = by + ly - 1, gx = bx + lx - 1;
        float v = 0.f;
        if ((unsigned)gy < 256u && (unsigned)gx < 256u)
            v = in[(((size_t)(b * 3 + cc)) << 16) + (gy << 8) + gx];
        ((float*)s_in)[i] = v;
    }
    __syncthreads();
    float acc[8];
#pragma unroll
    for (int k = 0; k < 8; ++k) acc[k] = 0.f;
    for (int cc = 0; cc < 3; ++cc) {
        float v[9];
#pragma unroll
        for (int dh = 0; dh < 3; ++dh)
#pragma unroll
            for (int dw = 0; dw < 3; ++dw)
                v[dh * 3 + dw] = s_in[cc][ty + dh][tx + dw];
        const float* wp = w + ((size_t)coBase * 3 + cc) * 9;
#pragma unroll
        for (int k = 0; k < 8; ++k) {
            const float* wk = wp + (size_t)k * 27;
            float a = acc[k];
#pragma unroll
            for (int j = 0; j < 9; ++j) a = fmaf(v[j], wk[j], a);
            acc[k] = a;
        }
    }
    const int h = by + ty, ww = bx + tx;
    unsigned short* op = out + (((size_t)(b * 256 + h)) * 256 + ww) * 32 + coBase;
#pragma unroll
    for (int k = 0; k < 8; ++k)
        op[k] = f2h(fmaxf(acc[k] + bias[coBase + k], 0.f));
}

// ---- 2x2 maxpool stride 2, NHWC fp16, 8 ch per thread ----
__global__ void poolh_k(const uint4* __restrict__ in, uint4* __restrict__ out,
                        int Ho, int Wo, int C8, int total)
{
    int i = blockIdx.x * 256 + threadIdx.x;
    if (i >= total) return;
    int oct = i % C8; int p = i / C8;
    int x = p % Wo; p /= Wo;
    int y = p % Ho; int b = p / Ho;
    const int H = Ho * 2, W = Wo * 2;
    size_t g = (((size_t)b * H + 2 * y) * W + 2 * x) * C8 + oct;
    uint4 v00 = in[g], v01 = in[g + C8];
    uint4 v10 = in[g + (size_t)W * C8], v11 = in[g + (size_t)W * C8 + C8];
    const unsigned short* a0 = (const unsigned short*)&v00;
    const unsigned short* a1 = (const unsigned short*)&v01;
    const unsigned short* a2 = (const unsigned short*)&v10;
    const unsigned short* a3 = (const unsigned short*)&v11;
    uint4 res; unsigned short* rp = (unsigned short*)&res;
#pragma unroll
    for (int j = 0; j < 8; ++j)
        rp[j] = f2h(fmaxf(fmaxf(h2f(a0[j]), h2f(a1[j])), fmaxf(h2f(a2[j]), h2f(a3[j]))));
    out[(((size_t)b * Ho + y) * Wo + x) * C8 + oct] = res;
}

// ---- fused 1x1 conv (MFMA 32x32) + row inclusive scan -> ii rows ----
// Block (y,b), 256 thr. Stage d1 row (256px x 32ch) + w16 to LDS; each wave
// computes 2 px-groups of 32 via 2x mfma_32x32x16; epilogue scatters to
// sout[co][px] (verified C/D map); then the 6-shfl scan per channel row.
__global__ __launch_bounds__(256) void rowprep_k(
    const uint4* __restrict__ in, const uint4* __restrict__ w16,
    const float* __restrict__ bias, float* __restrict__ ii)
{
    __shared__ uint4 sIn[1024];     // [px][oct]
    __shared__ uint4 sW[128];       // [koct][co]
    __shared__ float sout[32][256];
    __shared__ float sb[32];
    const int tid = threadIdx.x;
    const int lane = tid & 63, wv = tid >> 6;
    const int l31 = lane & 31, l5 = lane >> 5;
    const int y = blockIdx.x, b = blockIdx.y;

    const uint4* ip = in + (((size_t)b * 256 + y) * 256) * 4;
#pragma unroll
    for (int it = 0; it < 4; ++it)
        lds_load16(ip + tid + it * 256, &sIn[tid + it * 256]);
    if (tid < 128) lds_load16(w16 + tid, &sW[tid]);
    if (tid < 32) sb[tid] = bias[tid];
    __syncthreads();

    const half8* hW = (const half8*)sW;
    const half8* hIn = (const half8*)sIn;
    half8 af0 = hW[l5 * 32 + l31];
    half8 af1 = hW[(2 + l5) * 32 + l31];
#pragma unroll
    for (int g = 0; g < 2; ++g) {
        const int p0 = wv * 64 + g * 32;
        half8 bf0 = hIn[(p0 + l31) * 4 + l5];
        half8 bf1 = hIn[(p0 + l31) * 4 + 2 + l5];
        f32x16 acc;
#pragma unroll
        for (int q = 0; q < 16; ++q) acc[q] = 0.f;
        acc = __builtin_amdgcn_mfma_f32_32x32x16_f16(af0, bf0, acc, 0, 0, 0);
        acc = __builtin_amdgcn_mfma_f32_32x32x16_f16(af1, bf1, acc, 0, 0, 0);
#pragma unroll
        for (int r = 0; r < 16; ++r) {
            const int co = (r & 3) + 8 * (r >> 2) + 4 * l5;
            sout[co][p0 + l31] = acc[r] + sb[co];
        }
    }
    __syncthreads();

    float* plane0 = ii + (size_t)(b * 32) * IIPLANE;
    if (y == 0) {
        for (int i = tid; i < 32 * 257; i += 256) {
            int c = i / 257, xx = i % 257;
            plane0[(size_t)c * IIPLANE + xx + 3] = 0.f;
        }
    }
    for (int cc = 0; cc < 8; ++cc) {
        const int c = wv * 8 + cc;
        float* prow = plane0 + (size_t)c * IIPLANE + (size_t)(y + 1) * IIROW;
        float4 v = *(const float4*)&sout[c][lane * 4];
        float s0 = v.x, s1 = s0 + v.y, s2 = s1 + v.z, s3 = s2 + v.w;
        float t = s3;
#pragma unroll
        for (int off = 1; off < 64; off <<= 1) {
            float u = __shfl_up(t, off);
            if (lane >= off) t += u;
        }
        const float base = t - s3;
        float4 o;
        o.x = base + s0; o.y = base + s1; o.z = base + s2; o.w = base + s3;
        *(float4*)(prow + 4 + lane * 4) = o;
        if (lane == 0) prow[3] = 0.f;
    }
}

// ---- segmented column scan: pass A (64-row segment column sums) ----
__global__ __launch_bounds__(256) void colA_k(const float* __restrict__ ii,
                                              float* __restrict__ S)
{
    const int p = blockIdx.x, s = blockIdx.y;
    const int x = threadIdx.x;
    const float* plane = ii + (size_t)p * IIPLANE;
    float acc = 0.f;
#pragma unroll 8
    for (int y = s * 64 + 1; y <= s * 64 + 64; ++y)
        acc += plane[(size_t)y * IIROW + x + 4];
    S[(p * 3 + s) * 256 + x] = acc;
}

// ---- segmented column scan: pass B (apply prefixes, in-place scan) ----
__global__ __launch_bounds__(256) void colB_k(float* __restrict__ ii,
                                              const float* __restrict__ S)
{
    const int p = blockIdx.x, s = blockIdx.y;
    const int x = threadIdx.x;
    float* plane = ii + (size_t)p * IIPLANE;
    float acc = 0.f;
    for (int t = 0; t < s; ++t) acc += S[(p * 3 + t) * 256 + x];
#pragma unroll 8
    for (int y = s * 64 + 1; y <= s * 64 + 64; ++y) {
        float* q = plane + (size_t)y * IIROW + x + 4;
        acc += *q;
        *q = acc;
    }
}

// ---- adaptive ROI pool via integral image -> pooled[b][n][49] ----
__global__ void pool_k(const float* __restrict__ ii, const int* __restrict__ rois,
                       float* __restrict__ pooled)
{
    int t = blockIdx.x * 256 + threadIdx.x;
    int k = t % 49; int nb = t / 49;
    int n = nb % 1056; int b = nb / 1056;
    int ki = k / 7, kj = k % 7;
    int x1, y1, x2, y2, c;
    if (n < 32) {
        x1 = 0; y1 = 0; x2 = 256; y2 = 256; c = n;
    } else {
        int r = (n - 32) >> 5;
        c = (n - 32) & 31;
        x1 = rois[r * 4 + 0]; y1 = rois[r * 4 + 1];
        x2 = rois[r * 4 + 2]; y2 = rois[r * 4 + 3];
    }
    const int h = y2 - y1, w = x2 - x1;
    const int sy = y1 + (ki * h) / 7, ey = y1 + ((ki + 1) * h + 6) / 7;
    const int sx = x1 + (kj * w) / 7, ex = x1 + ((kj + 1) * w + 6) / 7;
    const float* pl = ii + (size_t)(b * 32 + c) * IIPLANE + 3;
    float s = pl[ey * IIROW + ex] - pl[sy * IIROW + ex]
            - pl[ey * IIROW + sx] + pl[sy * IIROW + sx];
    pooled[t] = s / (float)((ey - sy) * (ex - sx));
}

// ---- FC: out[b,n,f] = pooled[b,n,:] . fcwT[:,f] + fcb[f] ----
__global__ __launch_bounds__(512) void fc_k(
    const float* __restrict__ pooled, const float* __restrict__ fcwT,
    const float* __restrict__ fcb, float* __restrict__ out)
{
    const int nt = blockIdx.x, b = blockIdx.y;
    const int f = threadIdx.x;
    float wr[49];
#pragma unroll
    for (int k = 0; k < 49; ++k) wr[k] = fcwT[k * 512 + f];
    const float base = fcb[f];
    const float* pr = pooled + ((size_t)b * 1056 + nt * 16) * 49;
    float* op = out + (((size_t)b * 1056 + nt * 16)) * 512 + f;
#pragma unroll
    for (int j = 0; j < 16; ++j) {
        float a = base;
#pragma unroll
        for (int k = 0; k < 49; ++k)
            a = fmaf(pr[j * 49 + k], wr[k], a);
        op[(size_t)j * 512] = a;
    }
}

extern "C" void kernel_launch(void* const* d_in, const int* in_sizes, int n_in,
                              void* d_out, int out_size, void* d_ws, size_t ws_size,
                              hipStream_t stream)
{
    const float* x    = (const float*)d_in[0];
    const int*   rois = (const int*)d_in[1];
    const float* e1w1 = (const float*)d_in[2];
    const float* e1b1 = (const float*)d_in[3];
    const float* e1w2 = (const float*)d_in[4];
    const float* e1b2 = (const float*)d_in[5];
    const float* e2w1 = (const float*)d_in[6];
    const float* e2b1 = (const float*)d_in[7];
    const float* e2w2 = (const float*)d_in[8];
    const float* e2b2 = (const float*)d_in[9];
    const float* bw1  = (const float*)d_in[10];
    const float* bb1  = (const float*)d_in[11];
    const float* bw2  = (const float*)d_in[12];
    const float* bb2  = (const float*)d_in[13];
    const float* u2w  = (const float*)d_in[14];
    const float* u2b  = (const float*)d_in[15];
    const float* d2w1 = (const float*)d_in[16];
    const float* d2b1 = (const float*)d_in[17];
    const float* d2w2 = (const float*)d_in[18];
    const float* d2b2 = (const float*)d_in[19];
    const float* u1w  = (const float*)d_in[20];
    const float* u1b  = (const float*)d_in[21];
    const float* d1w1 = (const float*)d_in[22];
    const float* d1b1 = (const float*)d_in[23];
    const float* d1w2 = (const float*)d_in[24];
    const float* d1b2 = (const float*)d_in[25];
    const float* fw   = (const float*)d_in[26];
    const float* fb   = (const float*)d_in[27];
    const float* fcw  = (const float*)d_in[28];
    const float* fcb  = (const float*)d_in[29];

    // ---- workspace: WT(4MB) A(33.5) D(16.8) E(16.8) B(33.5) C(8.4) F(68.5)
    char* wsb = (char*)d_ws;
    char* WT = wsb;
    char* A  = wsb + 4194304;
    char* D  = A + 33554432;
    char* E  = D + 16777216;
    char* Bb = E + 16777216;
    char* C  = Bb + 33554432;
    char* F  = C + 8388608;
    float* ii     = (float*)F;
    float* fcwT   = (float*)(WT + 1179648);        // after conv weights (~1.03 MB)
    unsigned short* fw16 = (unsigned short*)(WT + 2097152);  // 8 KB
    uint4* zp     = (uint4*)(WT + 4194304 - 8192);
    float* pooled = (float*)C;
    float* Sbuf   = (float*)(C + 2097152);
    hipMemsetAsync(zp, 0, 8192, stream);

    // ---- weight transforms ----
    const float* wsrc[11] = {e1w2, e2w1, e2w2, bw1, bw2, u2w, d2w1, d2w2, u1w, d1w1, d1w2};
    const int wco[11] = {32, 64, 64, 128, 128, 64, 64, 64, 32, 32, 32};
    const int wci[11] = {32, 32, 64, 64, 128, 128, 128, 64, 64, 64, 32};
    size_t woff[11]; size_t o = 0;
    for (int i = 0; i < 11; ++i) { woff[i] = o; o += (size_t)wco[i] * wci[i] * 18; }
    for (int i = 0; i < 11; ++i) {
        int total = wco[i] * wci[i] * 9;
        hipLaunchKernelGGL(wprep_k, dim3((total + 255) / 256), dim3(256), 0, stream,
                           wsrc[i], (unsigned short*)(WT + woff[i]), wco[i], wci[i], total);
    }
    hipLaunchKernelGGL(fct_k, dim3((49 * 512 + 255) / 256), dim3(256), 0, stream, fcw, fcwT);
    hipLaunchKernelGGL(w1prep_k, dim3(16), dim3(256), 0, stream, fw, fw16);
    auto WP = [&](int i) { return (const uint4*)(WT + woff[i]); };

    #define CV1(i1,C1,i2,C2,wi,bs,ot,Cout,up,rl) \
        hipLaunchKernelGGL((convm2_k<32,64,8,8,up>), dim3(4,32,8*((Cout)/32)), dim3(256), 0, stream, \
            (const uint4*)(i1), (C1)/8, (const uint4*)(i2), (C2)/8, WP(wi), bs, \
            (unsigned short*)(ot), Cout, rl, zp)
    #define CV2(i1,C1,i2,C2,wi,bs,ot,Cout,up,rl) \
        hipLaunchKernelGGL((convm2_k<64,64,8,7,up>), dim3(2,16,8*((Cout)/64)), dim3(256), 0, stream, \
            (const uint4*)(i1), (C1)/8, (const uint4*)(i2), (C2)/8, WP(wi), bs, \
            (unsigned short*)(ot), Cout, rl, zp)
    #define CV3(i1,C1,i2,C2,wi,bs,ot,Cout,up,rl) \
        hipLaunchKernelGGL((convm2_k<64,64,4,6,up>), dim3(1,16,8*((Cout)/64)), dim3(256), 0, stream, \
            (const uint4*)(i1), (C1)/8, (const uint4*)(i2), (C2)/8, WP(wi), bs, \
            (unsigned short*)(ot), Cout, rl, zp)

    // encoder
    hipLaunchKernelGGL(conv0_k, dim3(16, 16, 32), dim3(16, 16), 0, stream,
                       x, e1w1, e1b1, (unsigned short*)A);        // e1a -> A
    CV1(A, 32, nullptr, 0, 0, e1b2, Bb, 32, 0, 1);               // e1  -> B
    {
        int N = 8 * 128 * 128 * 4;
        hipLaunchKernelGGL(poolh_k, dim3((N + 255) / 256), dim3(256), 0, stream,
                           (const uint4*)Bb, (uint4*)C, 128, 128, 4, N);  // p1 -> C
    }
    CV2(C, 32, nullptr, 0, 1, e2b1, A, 64, 0, 1);                // e2a -> A
    CV2(A, 64, nullptr, 0, 2, e2b2, D, 64, 0, 1);                // e2  -> D
    {
        int N = 8 * 64 * 64 * 8;
        hipLaunchKernelGGL(poolh_k, dim3((N + 255) / 256), dim3(256), 0, stream,
                           (const uint4*)D, (uint4*)C, 64, 64, 8, N);     // p2 -> C
    }
    // bottleneck
    CV3(C, 64, nullptr, 0, 3, bb1, E, 128, 0, 1);                // b1 -> E
    CV3(E, 128, nullptr, 0, 4, bb2, A, 128, 0, 1);               // b2 -> A
    // decoder level 2
    CV2(A, 128, nullptr, 0, 5, u2b, E, 64, 1, 1);                // u2 -> E (upsample)
    CV2(E, 64, D, 64, 6, d2b1, A, 64, 0, 1);                     // d2a -> A (concat)
    CV2(A, 64, nullptr, 0, 7, d2b2, D, 64, 0, 1);                // d2 -> D
    // decoder level 1
    CV1(D, 64, nullptr, 0, 8, u1b, A, 32, 1, 1);                 // u1 -> A (upsample)
    CV1(A, 32, Bb, 32, 9, d1b1, D, 32, 0, 1);                    // d1a -> D+E (concat)
    CV1(D, 32, nullptr, 0, 10, d1b2, Bb, 32, 0, 1);              // d1 -> B
    // fused 1x1 conv (MFMA) + row scan -> ii rows
    hipLaunchKernelGGL(rowprep_k, dim3(256, 8), dim3(256), 0, stream,
                       (const uint4*)Bb, (const uint4*)fw16, fb, ii);
    // segmented column scan
    hipLaunchKernelGGL(colA_k, dim3(256, 3), dim3(256), 0, stream, ii, Sbuf);
    hipLaunchKernelGGL(colB_k, dim3(256, 4), dim3(256), 0, stream, ii, Sbuf);
    // ROI pool + FC
    hipLaunchKernelGGL(pool_k, dim3(8 * 1056 * 49 / 256), dim3(256), 0, stream,
                       ii, rois, pooled);
    hipLaunchKernelGGL(fc_k, dim3(66, 8), dim3(512), 0, stream,
                       pooled, fcwT, fcb, (float*)d_out);
    #undef CV1
    #undef CV2
    #undef CV3
}

// Round 9
// 400.721 us; speedup vs baseline: 1.3035x; 1.0533x over previous
//
#include <hip/hip_runtime.h>

typedef _Float16 half8 __attribute__((ext_vector_type(8)));
typedef float f32x4 __attribute__((ext_vector_type(4)));
typedef float f32x16 __attribute__((ext_vector_type(16)));

__device__ __forceinline__ unsigned short f2h(float f) {
    _Float16 h = (_Float16)f;
    return __builtin_bit_cast(unsigned short, h);
}
__device__ __forceinline__ float h2f(unsigned short u) {
    return (float)__builtin_bit_cast(_Float16, u);
}

// async global->LDS, 16 B per lane; LDS dest linear (base + lane*16)
__device__ __forceinline__ void lds_load16(const uint4* g, uint4* l) {
    __builtin_amdgcn_global_load_lds(
        (const __attribute__((address_space(1))) unsigned int*)g,
        (__attribute__((address_space(3))) unsigned int*)l, 16, 0, 0);
}

// integral image layout: +3 offset so x=1+4k is 16B-aligned
#define IIROW 260
#define IIPLANE 66824

// ---- weight transform: OIHW fp32 -> [ck][pos][oct(ci/8)][co][ci&7] fp16 ----
__global__ void wprep_k(const float* __restrict__ src, unsigned short* __restrict__ dst,
                        int Cout, int Cin, int total)
{
    int t = blockIdx.x * 256 + threadIdx.x;
    if (t >= total) return;
    int j = t & 7; int r = t >> 3;
    int co = r % Cout; r /= Cout;
    int oct = r & 3; r >>= 2;
    int pos = r % 9; int ck = r / 9;
    int ci = ck * 32 + oct * 8 + j;
    dst[t] = f2h(src[((size_t)co * Cin + ci) * 9 + pos]);
}

// ---- 1x1 weight transform: fw[co][ci] fp32 -> [koct(4)][co(32)][ci&7] fp16 ----
__global__ void w1prep_k(const float* __restrict__ src, unsigned short* __restrict__ dst)
{
    int t = blockIdx.x * 256 + threadIdx.x;
    if (t >= 4096) return;
    int j = t & 7, co = (t >> 3) & 31, koct = t >> 8;
    dst[t] = f2h(src[co * 32 + koct * 8 + j]);
}

// ---- fc weight transpose: fcw[f][k] -> fcwT[k][f] (49 x 512) ----
__global__ void fct_k(const float* __restrict__ src, float* __restrict__ dst)
{
    int t = blockIdx.x * 256 + threadIdx.x;
    if (t >= 49 * 512) return;
    int k = t >> 9, f = t & 511;
    dst[t] = src[f * 49 + k];
}

// ---- MFMA conv3x3 SAME, NHWC fp16, fp32 accum; 2D tiles, async staging ----
template<int BM, int TW, int TH, int LW, int UP>
__global__ __launch_bounds__(256) void convm2_k(
    const uint4* __restrict__ in1, int C1g,
    const uint4* __restrict__ in2, int C2g,
    const uint4* __restrict__ wt,
    const float* __restrict__ bias,
    unsigned short* __restrict__ out,
    int Cout, int relu, const uint4* __restrict__ zp)
{
    constexpr int NM = BM / 16;
    constexpr int NN = (TW * TH) / 64;
    constexpr int Wf = 1 << LW, Hf = Wf;
    constexpr int WC = TW + 2, HR = TH + 2;
    constexpr int IN_GR = 4 * HR * WC;
    constexpr int LTW = (TW == 64) ? 6 : ((TW == 32) ? 5 : 7);
    constexpr int sH = UP ? (Hf >> 1) : Hf;
    constexpr int sW = UP ? (Wf >> 1) : Wf;
    __shared__ uint4 smem[IN_GR + 36 * BM];

    const int tid = threadIdx.x;
    const int lane = tid & 63, wv = tid >> 6;
    const int ng = Cout / BM;
    const int b = blockIdx.z / ng, cg = blockIdx.z % ng;
    const int x0 = blockIdx.x * TW, y0 = blockIdx.y * TH;
    const int NCK = (C1g + C2g) / 4;

    f32x4 acc[NM][NN];
#pragma unroll
    for (int m = 0; m < NM; ++m)
#pragma unroll
        for (int n = 0; n < NN; ++n) acc[m][n] = (f32x4){0.f, 0.f, 0.f, 0.f};

    const int l15 = lane & 15, l4 = lane >> 4;
    const int laneB = l4 * HR * WC + l15;
    const int laneA = l4 * BM + l15;

    for (int ck = 0; ck < NCK; ++ck) {
        if (ck) __syncthreads();
        {
            const uint4* src; int cg0, srcCg;
            if (ck * 4 < C1g) { src = in1; cg0 = ck * 4; srcCg = C1g; }
            else              { src = in2; cg0 = ck * 4 - C1g; srcCg = C2g; }
            for (int i = tid; i < IN_GR; i += 256) {
                int oct = i / (HR * WC);
                int rem = i - oct * (HR * WC);
                int row = rem / WC;
                int col = rem - row * WC;
                int gy = y0 + row - 1, gx = x0 + col - 1;
                int sy = UP ? (gy >> 1) : gy, sx = UP ? (gx >> 1) : gx;
                const uint4* ga = ((unsigned)gy < (unsigned)Hf && (unsigned)gx < (unsigned)Wf)
                    ? src + ((((size_t)b * sH + sy) * sW + sx) * srcCg + cg0 + oct)
                    : zp + (i & 63);
                lds_load16(ga, &smem[i]);
            }
        }
        {
            const uint4* wck = wt + (size_t)ck * 36 * Cout + (size_t)cg * BM;
            for (int i = tid; i < 36 * BM; i += 256) {
                int seg = i / BM, col = i - seg * BM;
                lds_load16(wck + seg * Cout + col, &smem[IN_GR + i]);
            }
        }
        __syncthreads();
        const half8* sB = (const half8*)smem;
        const half8* sA = (const half8*)(smem + IN_GR);
#pragma unroll
        for (int pos = 0; pos < 9; ++pos) {
            const int dr = pos / 3, dc = pos - dr * 3;
            half8 af[NM], bfr[NN];
#pragma unroll
            for (int m = 0; m < NM; ++m)
                af[m] = sA[pos * 4 * BM + m * 16 + laneA];
#pragma unroll
            for (int n = 0; n < NN; ++n) {
                const int pb = wv * (NN * 16) + n * 16;
                const int rn = (pb >> LTW) + dr;
                const int xn = (pb & (TW - 1)) + dc;
                bfr[n] = sB[rn * WC + xn + laneB];
            }
#pragma unroll
            for (int m = 0; m < NM; ++m)
#pragma unroll
                for (int n = 0; n < NN; ++n)
                    acc[m][n] = __builtin_amdgcn_mfma_f32_16x16x32_f16(af[m], bfr[n], acc[m][n], 0, 0, 0);
        }
    }

#pragma unroll
    for (int m = 0; m < NM; ++m) {
        const int co0 = cg * BM + m * 16 + l4 * 4;
        const float4 bs = *(const float4*)(bias + co0);
#pragma unroll
        for (int n = 0; n < NN; ++n) {
            const int pix = wv * (NN * 16) + n * 16 + l15;
            const int y = y0 + (pix >> LTW), x = x0 + (pix & (TW - 1));
            float v0 = acc[m][n][0] + bs.x;
            float v1 = acc[m][n][1] + bs.y;
            float v2 = acc[m][n][2] + bs.z;
            float v3 = acc[m][n][3] + bs.w;
            if (relu) {
                v0 = fmaxf(v0, 0.f); v1 = fmaxf(v1, 0.f);
                v2 = fmaxf(v2, 0.f); v3 = fmaxf(v3, 0.f);
            }
            uint2 pk;
            pk.x = (unsigned)f2h(v0) | ((unsigned)f2h(v1) << 16);
            pk.y = (unsigned)f2h(v2) | ((unsigned)f2h(v3) << 16);
            *(uint2*)(out + (((size_t)b * Hf + y) * Wf + x) * Cout + co0) = pk;
        }
    }
}

// ---- first conv 3->32, fp32 direct, NCHW fp32 in -> NHWC fp16 out ----
__global__ __launch_bounds__(256) void conv0_k(
    const float* __restrict__ in, const float* __restrict__ w,
    const float* __restrict__ bias, unsigned short* __restrict__ out)
{
    __shared__ float s_in[3][18][18];
    const int tx = threadIdx.x, ty = threadIdx.y;
    const int tid = ty * 16 + tx;
    const int b = blockIdx.z >> 2;
    const int coBase = (blockIdx.z & 3) * 8;
    const int bx = blockIdx.x * 16, by = blockIdx.y * 16;

    for (int i = tid; i < 3 * 18 * 18; i += 256) {
        int cc = i / 324, r = i % 324;
        int ly = r / 18, lx = r % 18;
        int gy = by + ly - 1, gx = bx + lx - 1;
        float v = 0.f;
        if ((unsigned)gy < 256u && (unsigned)gx < 256u)
            v = in[(((size_t)(b * 3 + cc)) << 16) + (gy << 8) + gx];
        ((float*)s_in)[i] = v;
    }
    __syncthreads();
    float acc[8];
#pragma unroll
    for (int k = 0; k < 8; ++k) acc[k] = 0.f;
    for (int cc = 0; cc < 3; ++cc) {
        float v[9];
#pragma unroll
        for (int dh = 0; dh < 3; ++dh)
#pragma unroll
            for (int dw = 0; dw < 3; ++dw)
                v[dh * 3 + dw] = s_in[cc][ty + dh][tx + dw];
        const float* wp = w + ((size_t)coBase * 3 + cc) * 9;
#pragma unroll
        for (int k = 0; k < 8; ++k) {
            const float* wk = wp + (size_t)k * 27;
            float a = acc[k];
#pragma unroll
            for (int j = 0; j < 9; ++j) a = fmaf(v[j], wk[j], a);
            acc[k] = a;
        }
    }
    const int h = by + ty, ww = bx + tx;
    unsigned short* op = out + (((size_t)(b * 256 + h)) * 256 + ww) * 32 + coBase;
#pragma unroll
    for (int k = 0; k < 8; ++k)
        op[k] = f2h(fmaxf(acc[k] + bias[coBase + k], 0.f));
}

// ---- 2x2 maxpool stride 2, NHWC fp16, 8 ch per thread ----
__global__ void poolh_k(const uint4* __restrict__ in, uint4* __restrict__ out,
                        int Ho, int Wo, int C8, int total)
{
    int i = blockIdx.x * 256 + threadIdx.x;
    if (i >= total) return;
    int oct = i % C8; int p = i / C8;
    int x = p % Wo; p /= Wo;
    int y = p % Ho; int b = p / Ho;
    const int H = Ho * 2, W = Wo * 2;
    size_t g = (((size_t)b * H + 2 * y) * W + 2 * x) * C8 + oct;
    uint4 v00 = in[g], v01 = in[g + C8];
    uint4 v10 = in[g + (size_t)W * C8], v11 = in[g + (size_t)W * C8 + C8];
    const unsigned short* a0 = (const unsigned short*)&v00;
    const unsigned short* a1 = (const unsigned short*)&v01;
    const unsigned short* a2 = (const unsigned short*)&v10;
    const unsigned short* a3 = (const unsigned short*)&v11;
    uint4 res; unsigned short* rp = (unsigned short*)&res;
#pragma unroll
    for (int j = 0; j < 8; ++j)
        rp[j] = f2h(fmaxf(fmaxf(h2f(a0[j]), h2f(a1[j])), fmaxf(h2f(a2[j]), h2f(a3[j]))));
    out[(((size_t)b * Ho + y) * Wo + x) * C8 + oct] = res;
}

// ---- fused 1x1 conv (MFMA 32x32) + row inclusive scan -> ii rows ----
__global__ __launch_bounds__(256) void rowprep_k(
    const uint4* __restrict__ in, const uint4* __restrict__ w16,
    const float* __restrict__ bias, float* __restrict__ ii)
{
    __shared__ uint4 sIn[1024];     // [px][oct]
    __shared__ uint4 sW[128];       // [koct][co]
    __shared__ float sout[32][256];
    __shared__ float sb[32];
    const int tid = threadIdx.x;
    const int lane = tid & 63, wv = tid >> 6;
    const int l31 = lane & 31, l5 = lane >> 5;
    const int y = blockIdx.x, b = blockIdx.y;

    const uint4* ip = in + (((size_t)b * 256 + y) * 256) * 4;
#pragma unroll
    for (int it = 0; it < 4; ++it)
        lds_load16(ip + tid + it * 256, &sIn[tid + it * 256]);
    if (tid < 128) lds_load16(w16 + tid, &sW[tid]);
    if (tid < 32) sb[tid] = bias[tid];
    __syncthreads();

    const half8* hW = (const half8*)sW;
    const half8* hIn = (const half8*)sIn;
    half8 af0 = hW[l5 * 32 + l31];
    half8 af1 = hW[(2 + l5) * 32 + l31];
#pragma unroll
    for (int g = 0; g < 2; ++g) {
        const int p0 = wv * 64 + g * 32;
        half8 bf0 = hIn[(p0 + l31) * 4 + l5];
        half8 bf1 = hIn[(p0 + l31) * 4 + 2 + l5];
        f32x16 acc;
#pragma unroll
        for (int q = 0; q < 16; ++q) acc[q] = 0.f;
        acc = __builtin_amdgcn_mfma_f32_32x32x16_f16(af0, bf0, acc, 0, 0, 0);
        acc = __builtin_amdgcn_mfma_f32_32x32x16_f16(af1, bf1, acc, 0, 0, 0);
#pragma unroll
        for (int r = 0; r < 16; ++r) {
            const int co = (r & 3) + 8 * (r >> 2) + 4 * l5;
            sout[co][p0 + l31] = acc[r] + sb[co];
        }
    }
    __syncthreads();

    float* plane0 = ii + (size_t)(b * 32) * IIPLANE;
    if (y == 0) {
        for (int i = tid; i < 32 * 257; i += 256) {
            int c = i / 257, xx = i % 257;
            plane0[(size_t)c * IIPLANE + xx + 3] = 0.f;
        }
    }
    for (int cc = 0; cc < 8; ++cc) {
        const int c = wv * 8 + cc;
        float* prow = plane0 + (size_t)c * IIPLANE + (size_t)(y + 1) * IIROW;
        float4 v = *(const float4*)&sout[c][lane * 4];
        float s0 = v.x, s1 = s0 + v.y, s2 = s1 + v.z, s3 = s2 + v.w;
        float t = s3;
#pragma unroll
        for (int off = 1; off < 64; off <<= 1) {
            float u = __shfl_up(t, off);
            if (lane >= off) t += u;
        }
        const float base = t - s3;
        float4 o;
        o.x = base + s0; o.y = base + s1; o.z = base + s2; o.w = base + s3;
        *(float4*)(prow + 4 + lane * 4) = o;
        if (lane == 0) prow[3] = 0.f;
    }
}

// ---- segmented column scan: pass A (64-row segment column sums) ----
__global__ __launch_bounds__(256) void colA_k(const float* __restrict__ ii,
                                              float* __restrict__ S)
{
    const int p = blockIdx.x, s = blockIdx.y;
    const int x = threadIdx.x;
    const float* plane = ii + (size_t)p * IIPLANE;
    float acc = 0.f;
#pragma unroll 8
    for (int y = s * 64 + 1; y <= s * 64 + 64; ++y)
        acc += plane[(size_t)y * IIROW + x + 4];
    S[(p * 3 + s) * 256 + x] = acc;
}

// ---- segmented column scan: pass B (apply prefixes, in-place scan) ----
__global__ __launch_bounds__(256) void colB_k(float* __restrict__ ii,
                                              const float* __restrict__ S)
{
    const int p = blockIdx.x, s = blockIdx.y;
    const int x = threadIdx.x;
    float* plane = ii + (size_t)p * IIPLANE;
    float acc = 0.f;
    for (int t = 0; t < s; ++t) acc += S[(p * 3 + t) * 256 + x];
#pragma unroll 8
    for (int y = s * 64 + 1; y <= s * 64 + 64; ++y) {
        float* q = plane + (size_t)y * IIROW + x + 4;
        acc += *q;
        *q = acc;
    }
}

// ---- adaptive ROI pool via integral image -> pooled[b][n][49] ----
__global__ void pool_k(const float* __restrict__ ii, const int* __restrict__ rois,
                       float* __restrict__ pooled)
{
    int t = blockIdx.x * 256 + threadIdx.x;
    int k = t % 49; int nb = t / 49;
    int n = nb % 1056; int b = nb / 1056;
    int ki = k / 7, kj = k % 7;
    int x1, y1, x2, y2, c;
    if (n < 32) {
        x1 = 0; y1 = 0; x2 = 256; y2 = 256; c = n;
    } else {
        int r = (n - 32) >> 5;
        c = (n - 32) & 31;
        x1 = rois[r * 4 + 0]; y1 = rois[r * 4 + 1];
        x2 = rois[r * 4 + 2]; y2 = rois[r * 4 + 3];
    }
    const int h = y2 - y1, w = x2 - x1;
    const int sy = y1 + (ki * h) / 7, ey = y1 + ((ki + 1) * h + 6) / 7;
    const int sx = x1 + (kj * w) / 7, ex = x1 + ((kj + 1) * w + 6) / 7;
    const float* pl = ii + (size_t)(b * 32 + c) * IIPLANE + 3;
    float s = pl[ey * IIROW + ex] - pl[sy * IIROW + ex]
            - pl[ey * IIROW + sx] + pl[sy * IIROW + sx];
    pooled[t] = s / (float)((ey - sy) * (ex - sx));
}

// ---- FC: out[b,n,f] = pooled[b,n,:] . fcwT[:,f] + fcb[f] ----
__global__ __launch_bounds__(512) void fc_k(
    const float* __restrict__ pooled, const float* __restrict__ fcwT,
    const float* __restrict__ fcb, float* __restrict__ out)
{
    const int nt = blockIdx.x, b = blockIdx.y;
    const int f = threadIdx.x;
    float wr[49];
#pragma unroll
    for (int k = 0; k < 49; ++k) wr[k] = fcwT[k * 512 + f];
    const float base = fcb[f];
    const float* pr = pooled + ((size_t)b * 1056 + nt * 16) * 49;
    float* op = out + (((size_t)b * 1056 + nt * 16)) * 512 + f;
#pragma unroll
    for (int j = 0; j < 16; ++j) {
        float a = base;
#pragma unroll
        for (int k = 0; k < 49; ++k)
            a = fmaf(pr[j * 49 + k], wr[k], a);
        op[(size_t)j * 512] = a;
    }
}

extern "C" void kernel_launch(void* const* d_in, const int* in_sizes, int n_in,
                              void* d_out, int out_size, void* d_ws, size_t ws_size,
                              hipStream_t stream)
{
    const float* x    = (const float*)d_in[0];
    const int*   rois = (const int*)d_in[1];
    const float* e1w1 = (const float*)d_in[2];
    const float* e1b1 = (const float*)d_in[3];
    const float* e1w2 = (const float*)d_in[4];
    const float* e1b2 = (const float*)d_in[5];
    const float* e2w1 = (const float*)d_in[6];
    const float* e2b1 = (const float*)d_in[7];
    const float* e2w2 = (const float*)d_in[8];
    const float* e2b2 = (const float*)d_in[9];
    const float* bw1  = (const float*)d_in[10];
    const float* bb1  = (const float*)d_in[11];
    const float* bw2  = (const float*)d_in[12];
    const float* bb2  = (const float*)d_in[13];
    const float* u2w  = (const float*)d_in[14];
    const float* u2b  = (const float*)d_in[15];
    const float* d2w1 = (const float*)d_in[16];
    const float* d2b1 = (const float*)d_in[17];
    const float* d2w2 = (const float*)d_in[18];
    const float* d2b2 = (const float*)d_in[19];
    const float* u1w  = (const float*)d_in[20];
    const float* u1b  = (const float*)d_in[21];
    const float* d1w1 = (const float*)d_in[22];
    const float* d1b1 = (const float*)d_in[23];
    const float* d1w2 = (const float*)d_in[24];
    const float* d1b2 = (const float*)d_in[25];
    const float* fw   = (const float*)d_in[26];
    const float* fb   = (const float*)d_in[27];
    const float* fcw  = (const float*)d_in[28];
    const float* fcb  = (const float*)d_in[29];

    // ---- workspace: WT(4MB) A(33.5) D(16.8) E(16.8) B(33.5) C(8.4) F(68.5)
    char* wsb = (char*)d_ws;
    char* WT = wsb;
    char* A  = wsb + 4194304;
    char* D  = A + 33554432;
    char* E  = D + 16777216;
    char* Bb = E + 16777216;
    char* C  = Bb + 33554432;
    char* F  = C + 8388608;
    float* ii     = (float*)F;
    float* fcwT   = (float*)(WT + 1179648);
    unsigned short* fw16 = (unsigned short*)(WT + 2097152);
    uint4* zp     = (uint4*)(WT + 4194304 - 8192);
    float* pooled = (float*)C;
    float* Sbuf   = (float*)(C + 2097152);
    hipMemsetAsync(zp, 0, 8192, stream);

    // ---- weight transforms ----
    const float* wsrc[11] = {e1w2, e2w1, e2w2, bw1, bw2, u2w, d2w1, d2w2, u1w, d1w1, d1w2};
    const int wco[11] = {32, 64, 64, 128, 128, 64, 64, 64, 32, 32, 32};
    const int wci[11] = {32, 32, 64, 64, 128, 128, 128, 64, 64, 64, 32};
    size_t woff[11]; size_t o = 0;
    for (int i = 0; i < 11; ++i) { woff[i] = o; o += (size_t)wco[i] * wci[i] * 18; }
    for (int i = 0; i < 11; ++i) {
        int total = wco[i] * wci[i] * 9;
        hipLaunchKernelGGL(wprep_k, dim3((total + 255) / 256), dim3(256), 0, stream,
                           wsrc[i], (unsigned short*)(WT + woff[i]), wco[i], wci[i], total);
    }
    hipLaunchKernelGGL(fct_k, dim3((49 * 512 + 255) / 256), dim3(256), 0, stream, fcw, fcwT);
    hipLaunchKernelGGL(w1prep_k, dim3(16), dim3(256), 0, stream, fw, fw16);
    auto WP = [&](int i) { return (const uint4*)(WT + woff[i]); };

    // CV1: 256², BM32, TH4 -> grid 2048, LDS 43.8 KB (3 blk/CU)
    // CV2: 128², BM64, TH4 -> grid 512,  LDS 62.2 KB (2 blk/CU)
    // CV3:  64², BM32, TH4 -> grid 512,  LDS 43.8 KB (3 blk/CU)
    #define CV1(i1,C1,i2,C2,wi,bs,ot,Cout,up,rl) \
        hipLaunchKernelGGL((convm2_k<32,64,4,8,up>), dim3(4,64,8*((Cout)/32)), dim3(256), 0, stream, \
            (const uint4*)(i1), (C1)/8, (const uint4*)(i2), (C2)/8, WP(wi), bs, \
            (unsigned short*)(ot), Cout, rl, zp)
    #define CV2(i1,C1,i2,C2,wi,bs,ot,Cout,up,rl) \
        hipLaunchKernelGGL((convm2_k<64,64,4,7,up>), dim3(2,32,8*((Cout)/64)), dim3(256), 0, stream, \
            (const uint4*)(i1), (C1)/8, (const uint4*)(i2), (C2)/8, WP(wi), bs, \
            (unsigned short*)(ot), Cout, rl, zp)
    #define CV3(i1,C1,i2,C2,wi,bs,ot,Cout,up,rl) \
        hipLaunchKernelGGL((convm2_k<32,64,4,6,up>), dim3(1,16,8*((Cout)/32)), dim3(256), 0, stream, \
            (const uint4*)(i1), (C1)/8, (const uint4*)(i2), (C2)/8, WP(wi), bs, \
            (unsigned short*)(ot), Cout, rl, zp)

    // encoder
    hipLaunchKernelGGL(conv0_k, dim3(16, 16, 32), dim3(16, 16), 0, stream,
                       x, e1w1, e1b1, (unsigned short*)A);        // e1a -> A
    CV1(A, 32, nullptr, 0, 0, e1b2, Bb, 32, 0, 1);               // e1  -> B
    {
        int N = 8 * 128 * 128 * 4;
        hipLaunchKernelGGL(poolh_k, dim3((N + 255) / 256), dim3(256), 0, stream,
                           (const uint4*)Bb, (uint4*)C, 128, 128, 4, N);  // p1 -> C
    }
    CV2(C, 32, nullptr, 0, 1, e2b1, A, 64, 0, 1);                // e2a -> A
    CV2(A, 64, nullptr, 0, 2, e2b2, D, 64, 0, 1);                // e2  -> D
    {
        int N = 8 * 64 * 64 * 8;
        hipLaunchKernelGGL(poolh_k, dim3((N + 255) / 256), dim3(256), 0, stream,
                           (const uint4*)D, (uint4*)C, 64, 64, 8, N);     // p2 -> C
    }
    // bottleneck
    CV3(C, 64, nullptr, 0, 3, bb1, E, 128, 0, 1);                // b1 -> E
    CV3(E, 128, nullptr, 0, 4, bb2, A, 128, 0, 1);               // b2 -> A
    // decoder level 2
    CV2(A, 128, nullptr, 0, 5, u2b, E, 64, 1, 1);                // u2 -> E (upsample)
    CV2(E, 64, D, 64, 6, d2b1, A, 64, 0, 1);                     // d2a -> A (concat)
    CV2(A, 64, nullptr, 0, 7, d2b2, D, 64, 0, 1);                // d2 -> D
    // decoder level 1
    CV1(D, 64, nullptr, 0, 8, u1b, A, 32, 1, 1);                 // u1 -> A (upsample)
    CV1(A, 32, Bb, 32, 9, d1b1, D, 32, 0, 1);                    // d1a -> D+E (concat)
    CV1(D, 32, nullptr, 0, 10, d1b2, Bb, 32, 0, 1);              // d1 -> B
    // fused 1x1 conv (MFMA) + row scan -> ii rows
    hipLaunchKernelGGL(rowprep_k, dim3(256, 8), dim3(256), 0, stream,
                       (const uint4*)Bb, (const uint4*)fw16, fb, ii);
    // segmented column scan
    hipLaunchKernelGGL(colA_k, dim3(256, 3), dim3(256), 0, stream, ii, Sbuf);
    hipLaunchKernelGGL(colB_k, dim3(256, 4), dim3(256), 0, stream, ii, Sbuf);
    // ROI pool + FC
    hipLaunchKernelGGL(pool_k, dim3(8 * 1056 * 49 / 256), dim3(256), 0, stream,
                       ii, rois, pooled);
    hipLaunchKernelGGL(fc_k, dim3(66, 8), dim3(512), 0, stream,
                       pooled, fcwT, fcb, (float*)d_out);
    #undef CV1
    #undef CV2
    #undef CV3
}

// Round 10
// 397.549 us; speedup vs baseline: 1.3139x; 1.0080x over previous
//
#include <hip/hip_runtime.h>

typedef _Float16 half8 __attribute__((ext_vector_type(8)));
typedef float f32x4 __attribute__((ext_vector_type(4)));
typedef float f32x16 __attribute__((ext_vector_type(16)));

__device__ __forceinline__ unsigned short f2h(float f) {
    _Float16 h = (_Float16)f;
    return __builtin_bit_cast(unsigned short, h);
}
__device__ __forceinline__ float h2f(unsigned short u) {
    return (float)__builtin_bit_cast(_Float16, u);
}

// async global->LDS, 16 B per lane; LDS dest linear (base + lane*16)
__device__ __forceinline__ void lds_load16(const uint4* g, uint4* l) {
    __builtin_amdgcn_global_load_lds(
        (const __attribute__((address_space(1))) unsigned int*)g,
        (__attribute__((address_space(3))) unsigned int*)l, 16, 0, 0);
}

// integral image layout: +3 offset so x=1+4k is 16B-aligned
#define IIROW 260
#define IIPLANE 66824

// ---- weight transform: OIHW fp32 -> [ck][pos][oct(ci/8)][co][ci&7] fp16 ----
__global__ void wprep_k(const float* __restrict__ src, unsigned short* __restrict__ dst,
                        int Cout, int Cin, int total)
{
    int t = blockIdx.x * 256 + threadIdx.x;
    if (t >= total) return;
    int j = t & 7; int r = t >> 3;
    int co = r % Cout; r /= Cout;
    int oct = r & 3; r >>= 2;
    int pos = r % 9; int ck = r / 9;
    int ci = ck * 32 + oct * 8 + j;
    dst[t] = f2h(src[((size_t)co * Cin + ci) * 9 + pos]);
}

// ---- 1x1 weight transform: fw[co][ci] fp32 -> [koct(4)][co(32)][ci&7] fp16 ----
__global__ void w1prep_k(const float* __restrict__ src, unsigned short* __restrict__ dst)
{
    int t = blockIdx.x * 256 + threadIdx.x;
    if (t >= 4096) return;
    int j = t & 7, co = (t >> 3) & 31, koct = t >> 8;
    dst[t] = f2h(src[co * 32 + koct * 8 + j]);
}

// ---- fc weight transpose: fcw[f][k] -> fcwT[k][f] (49 x 512) ----
__global__ void fct_k(const float* __restrict__ src, float* __restrict__ dst)
{
    int t = blockIdx.x * 256 + threadIdx.x;
    if (t >= 49 * 512) return;
    int k = t >> 9, f = t & 511;
    dst[t] = src[f * 49 + k];
}

// ---- MFMA conv3x3 SAME, NHWC fp16, fp32 accum; row-reuse B-fragment loop ----
// Each wave owns RQ=2 output rows; B-fragments for the 4 tap-rows are read once
// per dc and reused across the 3 dr taps (cuts B LDS reads by 1/3).
template<int BM, int TW, int TH, int LW, int UP>
__global__ __launch_bounds__(256, 2) void convm4_k(
    const uint4* __restrict__ in1, int C1g,
    const uint4* __restrict__ in2, int C2g,
    const uint4* __restrict__ wt,
    const float* __restrict__ bias,
    unsigned short* __restrict__ out,
    int Cout, int relu, const uint4* __restrict__ zp)
{
    constexpr int NM = BM / 16;
    constexpr int NN = (TW * TH) / 64;
    constexpr int CG = TW / 16;       // col groups per row
    constexpr int RQ = NN / CG;       // rows per wave (must be 2)
    static_assert(RQ == 2, "row-reuse layout needs 2 rows/wave");
    constexpr int Wf = 1 << LW, Hf = Wf;
    constexpr int WC = TW + 2, HR = TH + 2;
    constexpr int IN_GR = 4 * HR * WC;
    constexpr int LTW = (TW == 64) ? 6 : 5;
    constexpr int sH = UP ? (Hf >> 1) : Hf;
    constexpr int sW = UP ? (Wf >> 1) : Wf;
    __shared__ uint4 smem[IN_GR + 36 * BM];

    const int tid = threadIdx.x;
    const int lane = tid & 63, wv = tid >> 6;
    const int ng = Cout / BM;
    const int b = blockIdx.z / ng, cg = blockIdx.z % ng;
    const int x0 = blockIdx.x * TW, y0 = blockIdx.y * TH;
    const int NCK = (C1g + C2g) / 4;

    f32x4 acc[NM][NN];
#pragma unroll
    for (int m = 0; m < NM; ++m)
#pragma unroll
        for (int n = 0; n < NN; ++n) acc[m][n] = (f32x4){0.f, 0.f, 0.f, 0.f};

    const int l15 = lane & 15, l4 = lane >> 4;
    const int laneB = l4 * HR * WC + l15;
    const int laneA = l4 * BM + l15;

    for (int ck = 0; ck < NCK; ++ck) {
        if (ck) __syncthreads();
        {
            const uint4* src; int cg0, srcCg;
            if (ck * 4 < C1g) { src = in1; cg0 = ck * 4; srcCg = C1g; }
            else              { src = in2; cg0 = ck * 4 - C1g; srcCg = C2g; }
            for (int i = tid; i < IN_GR; i += 256) {
                int oct = i / (HR * WC);
                int rem = i - oct * (HR * WC);
                int row = rem / WC;
                int col = rem - row * WC;
                int gy = y0 + row - 1, gx = x0 + col - 1;
                int sy = UP ? (gy >> 1) : gy, sx = UP ? (gx >> 1) : gx;
                const uint4* ga = ((unsigned)gy < (unsigned)Hf && (unsigned)gx < (unsigned)Wf)
                    ? src + ((((size_t)b * sH + sy) * sW + sx) * srcCg + cg0 + oct)
                    : zp + (i & 63);
                lds_load16(ga, &smem[i]);
            }
        }
        {
            const uint4* wck = wt + (size_t)ck * 36 * Cout + (size_t)cg * BM;
            for (int i = tid; i < 36 * BM; i += 256) {
                int seg = i / BM, col = i - seg * BM;
                lds_load16(wck + seg * Cout + col, &smem[IN_GR + i]);
            }
        }
        __syncthreads();
        const half8* sB = (const half8*)smem;
        const half8* sA = (const half8*)(smem + IN_GR);
#pragma unroll
        for (int dc = 0; dc < 3; ++dc) {
            half8 br[RQ + 2][CG];
#pragma unroll
            for (int r = 0; r < RQ + 2; ++r)
#pragma unroll
                for (int c2 = 0; c2 < CG; ++c2)
                    br[r][c2] = sB[(wv * RQ + r) * WC + c2 * 16 + dc + laneB];
#pragma unroll
            for (int dr = 0; dr < 3; ++dr) {
                half8 af[NM];
#pragma unroll
                for (int m = 0; m < NM; ++m)
                    af[m] = sA[(dr * 3 + dc) * 4 * BM + m * 16 + laneA];
#pragma unroll
                for (int m = 0; m < NM; ++m)
#pragma unroll
                    for (int rq = 0; rq < RQ; ++rq)
#pragma unroll
                        for (int c2 = 0; c2 < CG; ++c2)
                            acc[m][rq * CG + c2] = __builtin_amdgcn_mfma_f32_16x16x32_f16(
                                af[m], br[rq + dr][c2], acc[m][rq * CG + c2], 0, 0, 0);
            }
        }
    }

#pragma unroll
    for (int m = 0; m < NM; ++m) {
        const int co0 = cg * BM + m * 16 + l4 * 4;
        const float4 bs = *(const float4*)(bias + co0);
#pragma unroll
        for (int n = 0; n < NN; ++n) {
            const int pix = wv * (NN * 16) + n * 16 + l15;
            const int y = y0 + (pix >> LTW), x = x0 + (pix & (TW - 1));
            float v0 = acc[m][n][0] + bs.x;
            float v1 = acc[m][n][1] + bs.y;
            float v2 = acc[m][n][2] + bs.z;
            float v3 = acc[m][n][3] + bs.w;
            if (relu) {
                v0 = fmaxf(v0, 0.f); v1 = fmaxf(v1, 0.f);
                v2 = fmaxf(v2, 0.f); v3 = fmaxf(v3, 0.f);
            }
            uint2 pk;
            pk.x = (unsigned)f2h(v0) | ((unsigned)f2h(v1) << 16);
            pk.y = (unsigned)f2h(v2) | ((unsigned)f2h(v3) << 16);
            *(uint2*)(out + (((size_t)b * Hf + y) * Wf + x) * Cout + co0) = pk;
        }
    }
}

// ---- first conv 3->32, fp32 direct, NCHW fp32 in -> NHWC fp16 out ----
__global__ __launch_bounds__(256) void conv0_k(
    const float* __restrict__ in, const float* __restrict__ w,
    const float* __restrict__ bias, unsigned short* __restrict__ out)
{
    __shared__ float s_in[3][18][18];
    const int tx = threadIdx.x, ty = threadIdx.y;
    const int tid = ty * 16 + tx;
    const int b = blockIdx.z >> 2;
    const int coBase = (blockIdx.z & 3) * 8;
    const int bx = blockIdx.x * 16, by = blockIdx.y * 16;

    for (int i = tid; i < 3 * 18 * 18; i += 256) {
        int cc = i / 324, r = i % 324;
        int ly = r / 18, lx = r % 18;
        int gy = by + ly - 1, gx = bx + lx - 1;
        float v = 0.f;
        if ((unsigned)gy < 256u && (unsigned)gx < 256u)
            v = in[(((size_t)(b * 3 + cc)) << 16) + (gy << 8) + gx];
        ((float*)s_in)[i] = v;
    }
    __syncthreads();
    float acc[8];
#pragma unroll
    for (int k = 0; k < 8; ++k) acc[k] = 0.f;
    for (int cc = 0; cc < 3; ++cc) {
        float v[9];
#pragma unroll
        for (int dh = 0; dh < 3; ++dh)
#pragma unroll
            for (int dw = 0; dw < 3; ++dw)
                v[dh * 3 + dw] = s_in[cc][ty + dh][tx + dw];
        const float* wp = w + ((size_t)coBase * 3 + cc) * 9;
#pragma unroll
        for (int k = 0; k < 8; ++k) {
            const float* wk = wp + (size_t)k * 27;
            float a = acc[k];
#pragma unroll
            for (int j = 0; j < 9; ++j) a = fmaf(v[j], wk[j], a);
            acc[k] = a;
        }
    }
    const int h = by + ty, ww = bx + tx;
    unsigned short* op = out + (((size_t)(b * 256 + h)) * 256 + ww) * 32 + coBase;
#pragma unroll
    for (int k = 0; k < 8; ++k)
        op[k] = f2h(fmaxf(acc[k] + bias[coBase + k], 0.f));
}

// ---- 2x2 maxpool stride 2, NHWC fp16, 8 ch per thread ----
__global__ void poolh_k(const uint4* __restrict__ in, uint4* __restrict__ out,
                        int Ho, int Wo, int C8, int total)
{
    int i = blockIdx.x * 256 + threadIdx.x;
    if (i >= total) return;
    int oct = i % C8; int p = i / C8;
    int x = p % Wo; p /= Wo;
    int y = p % Ho; int b = p / Ho;
    const int H = Ho * 2, W = Wo * 2;
    size_t g = (((size_t)b * H + 2 * y) * W + 2 * x) * C8 + oct;
    uint4 v00 = in[g], v01 = in[g + C8];
    uint4 v10 = in[g + (size_t)W * C8], v11 = in[g + (size_t)W * C8 + C8];
    const unsigned short* a0 = (const unsigned short*)&v00;
    const unsigned short* a1 = (const unsigned short*)&v01;
    const unsigned short* a2 = (const unsigned short*)&v10;
    const unsigned short* a3 = (const unsigned short*)&v11;
    uint4 res; unsigned short* rp = (unsigned short*)&res;
#pragma unroll
    for (int j = 0; j < 8; ++j)
        rp[j] = f2h(fmaxf(fmaxf(h2f(a0[j]), h2f(a1[j])), fmaxf(h2f(a2[j]), h2f(a3[j]))));
    out[(((size_t)b * Ho + y) * Wo + x) * C8 + oct] = res;
}

// ---- fused 1x1 conv (MFMA 32x32) + row inclusive scan -> ii rows ----
__global__ __launch_bounds__(256) void rowprep_k(
    const uint4* __restrict__ in, const uint4* __restrict__ w16,
    const float* __restrict__ bias, float* __restrict__ ii)
{
    __shared__ uint4 sIn[1024];     // [px][oct]
    __shared__ uint4 sW[128];       // [koct][co]
    __shared__ float sout[32][256];
    __shared__ float sb[32];
    const int tid = threadIdx.x;
    const int lane = tid & 63, wv = tid >> 6;
    const int l31 = lane & 31, l5 = lane >> 5;
    const int y = blockIdx.x, b = blockIdx.y;

    const uint4* ip = in + (((size_t)b * 256 + y) * 256) * 4;
#pragma unroll
    for (int it = 0; it < 4; ++it)
        lds_load16(ip + tid + it * 256, &sIn[tid + it * 256]);
    if (tid < 128) lds_load16(w16 + tid, &sW[tid]);
    if (tid < 32) sb[tid] = bias[tid];
    __syncthreads();

    const half8* hW = (const half8*)sW;
    const half8* hIn = (const half8*)sIn;
    half8 af0 = hW[l5 * 32 + l31];
    half8 af1 = hW[(2 + l5) * 32 + l31];
#pragma unroll
    for (int g = 0; g < 2; ++g) {
        const int p0 = wv * 64 + g * 32;
        half8 bf0 = hIn[(p0 + l31) * 4 + l5];
        half8 bf1 = hIn[(p0 + l31) * 4 + 2 + l5];
        f32x16 acc;
#pragma unroll
        for (int q = 0; q < 16; ++q) acc[q] = 0.f;
        acc = __builtin_amdgcn_mfma_f32_32x32x16_f16(af0, bf0, acc, 0, 0, 0);
        acc = __builtin_amdgcn_mfma_f32_32x32x16_f16(af1, bf1, acc, 0, 0, 0);
#pragma unroll
        for (int r = 0; r < 16; ++r) {
            const int co = (r & 3) + 8 * (r >> 2) + 4 * l5;
            sout[co][p0 + l31] = acc[r] + sb[co];
        }
    }
    __syncthreads();

    float* plane0 = ii + (size_t)(b * 32) * IIPLANE;
    if (y == 0) {
        for (int i = tid; i < 32 * 257; i += 256) {
            int c = i / 257, xx = i % 257;
            plane0[(size_t)c * IIPLANE + xx + 3] = 0.f;
        }
    }
    for (int cc = 0; cc < 8; ++cc) {
        const int c = wv * 8 + cc;
        float* prow = plane0 + (size_t)c * IIPLANE + (size_t)(y + 1) * IIROW;
        float4 v = *(const float4*)&sout[c][lane * 4];
        float s0 = v.x, s1 = s0 + v.y, s2 = s1 + v.z, s3 = s2 + v.w;
        float t = s3;
#pragma unroll
        for (int off = 1; off < 64; off <<= 1) {
            float u = __shfl_up(t, off);
            if (lane >= off) t += u;
        }
        const float base = t - s3;
        float4 o;
        o.x = base + s0; o.y = base + s1; o.z = base + s2; o.w = base + s3;
        *(float4*)(prow + 4 + lane * 4) = o;
        if (lane == 0) prow[3] = 0.f;
    }
}

// ---- segmented column scan: pass A (64-row segment column sums) ----
__global__ __launch_bounds__(256) void colA_k(const float* __restrict__ ii,
                                              float* __restrict__ S)
{
    const int p = blockIdx.x, s = blockIdx.y;
    const int x = threadIdx.x;
    const float* plane = ii + (size_t)p * IIPLANE;
    float acc = 0.f;
#pragma unroll 8
    for (int y = s * 64 + 1; y <= s * 64 + 64; ++y)
        acc += plane[(size_t)y * IIROW + x + 4];
    S[(p * 3 + s) * 256 + x] = acc;
}

// ---- segmented column scan: pass B (apply prefixes, in-place scan) ----
__global__ __launch_bounds__(256) void colB_k(float* __restrict__ ii,
                                              const float* __restrict__ S)
{
    const int p = blockIdx.x, s = blockIdx.y;
    const int x = threadIdx.x;
    float* plane = ii + (size_t)p * IIPLANE;
    float acc = 0.f;
    for (int t = 0; t < s; ++t) acc += S[(p * 3 + t) * 256 + x];
#pragma unroll 8
    for (int y = s * 64 + 1; y <= s * 64 + 64; ++y) {
        float* q = plane + (size_t)y * IIROW + x + 4;
        acc += *q;
        *q = acc;
    }
}

// ---- adaptive ROI pool via integral image -> pooled[b][n][49] ----
__global__ void pool_k(const float* __restrict__ ii, const int* __restrict__ rois,
                       float* __restrict__ pooled)
{
    int t = blockIdx.x * 256 + threadIdx.x;
    int k = t % 49; int nb = t / 49;
    int n = nb % 1056; int b = nb / 1056;
    int ki = k / 7, kj = k % 7;
    int x1, y1, x2, y2, c;
    if (n < 32) {
        x1 = 0; y1 = 0; x2 = 256; y2 = 256; c = n;
    } else {
        int r = (n - 32) >> 5;
        c = (n - 32) & 31;
        x1 = rois[r * 4 + 0]; y1 = rois[r * 4 + 1];
        x2 = rois[r * 4 + 2]; y2 = rois[r * 4 + 3];
    }
    const int h = y2 - y1, w = x2 - x1;
    const int sy = y1 + (ki * h) / 7, ey = y1 + ((ki + 1) * h + 6) / 7;
    const int sx = x1 + (kj * w) / 7, ex = x1 + ((kj + 1) * w + 6) / 7;
    const float* pl = ii + (size_t)(b * 32 + c) * IIPLANE + 3;
    float s = pl[ey * IIROW + ex] - pl[sy * IIROW + ex]
            - pl[ey * IIROW + sx] + pl[sy * IIROW + sx];
    pooled[t] = s / (float)((ey - sy) * (ex - sx));
}

// ---- FC: out[b,n,f] = pooled[b,n,:] . fcwT[:,f] + fcb[f] ----
__global__ __launch_bounds__(512) void fc_k(
    const float* __restrict__ pooled, const float* __restrict__ fcwT,
    const float* __restrict__ fcb, float* __restrict__ out)
{
    const int nt = blockIdx.x, b = blockIdx.y;
    const int f = threadIdx.x;
    float wr[49];
#pragma unroll
    for (int k = 0; k < 49; ++k) wr[k] = fcwT[k * 512 + f];
    const float base = fcb[f];
    const float* pr = pooled + ((size_t)b * 1056 + nt * 16) * 49;
    float* op = out + (((size_t)b * 1056 + nt * 16)) * 512 + f;
#pragma unroll
    for (int j = 0; j < 16; ++j) {
        float a = base;
#pragma unroll
        for (int k = 0; k < 49; ++k)
            a = fmaf(pr[j * 49 + k], wr[k], a);
        op[(size_t)j * 512] = a;
    }
}

extern "C" void kernel_launch(void* const* d_in, const int* in_sizes, int n_in,
                              void* d_out, int out_size, void* d_ws, size_t ws_size,
                              hipStream_t stream)
{
    const float* x    = (const float*)d_in[0];
    const int*   rois = (const int*)d_in[1];
    const float* e1w1 = (const float*)d_in[2];
    const float* e1b1 = (const float*)d_in[3];
    const float* e1w2 = (const float*)d_in[4];
    const float* e1b2 = (const float*)d_in[5];
    const float* e2w1 = (const float*)d_in[6];
    const float* e2b1 = (const float*)d_in[7];
    const float* e2w2 = (const float*)d_in[8];
    const float* e2b2 = (const float*)d_in[9];
    const float* bw1  = (const float*)d_in[10];
    const float* bb1  = (const float*)d_in[11];
    const float* bw2  = (const float*)d_in[12];
    const float* bb2  = (const float*)d_in[13];
    const float* u2w  = (const float*)d_in[14];
    const float* u2b  = (const float*)d_in[15];
    const float* d2w1 = (const float*)d_in[16];
    const float* d2b1 = (const float*)d_in[17];
    const float* d2w2 = (const float*)d_in[18];
    const float* d2b2 = (const float*)d_in[19];
    const float* u1w  = (const float*)d_in[20];
    const float* u1b  = (const float*)d_in[21];
    const float* d1w1 = (const float*)d_in[22];
    const float* d1b1 = (const float*)d_in[23];
    const float* d1w2 = (const float*)d_in[24];
    const float* d1b2 = (const float*)d_in[25];
    const float* fw   = (const float*)d_in[26];
    const float* fb   = (const float*)d_in[27];
    const float* fcw  = (const float*)d_in[28];
    const float* fcb  = (const float*)d_in[29];

    // ---- workspace: WT(4MB) A(33.5) D(16.8) E(16.8) B(33.5) C(8.4) F(68.5)
    char* wsb = (char*)d_ws;
    char* WT = wsb;
    char* A  = wsb + 4194304;
    char* D  = A + 33554432;
    char* E  = D + 16777216;
    char* Bb = E + 16777216;
    char* C  = Bb + 33554432;
    char* F  = C + 8388608;
    float* ii     = (float*)F;
    float* fcwT   = (float*)(WT + 1179648);
    unsigned short* fw16 = (unsigned short*)(WT + 2097152);
    uint4* zp     = (uint4*)(WT + 4194304 - 8192);
    float* pooled = (float*)C;
    float* Sbuf   = (float*)(C + 2097152);
    hipMemsetAsync(zp, 0, 8192, stream);

    // ---- weight transforms ----
    const float* wsrc[11] = {e1w2, e2w1, e2w2, bw1, bw2, u2w, d2w1, d2w2, u1w, d1w1, d1w2};
    const int wco[11] = {32, 64, 64, 128, 128, 64, 64, 64, 32, 32, 32};
    const int wci[11] = {32, 32, 64, 64, 128, 128, 128, 64, 64, 64, 32};
    size_t woff[11]; size_t o = 0;
    for (int i = 0; i < 11; ++i) { woff[i] = o; o += (size_t)wco[i] * wci[i] * 18; }
    for (int i = 0; i < 11; ++i) {
        int total = wco[i] * wci[i] * 9;
        hipLaunchKernelGGL(wprep_k, dim3((total + 255) / 256), dim3(256), 0, stream,
                           wsrc[i], (unsigned short*)(WT + woff[i]), wco[i], wci[i], total);
    }
    hipLaunchKernelGGL(fct_k, dim3((49 * 512 + 255) / 256), dim3(256), 0, stream, fcw, fcwT);
    hipLaunchKernelGGL(w1prep_k, dim3(16), dim3(256), 0, stream, fw, fw16);
    auto WP = [&](int i) { return (const uint4*)(WT + woff[i]); };

    // CV1: 256², BM32 TW64 TH8 -> grid 1024·ng, LDS 60.7 KB (2 blk/CU)
    // CV2: 128², BM64 TW32 TH8 -> grid 512,     LDS 58.6 KB (2 blk/CU)
    // CV3:  64², BM32 TW32 TH8 -> grid 512,     LDS 40.2 KB (2+ blk/CU)
    #define CV1(i1,C1,i2,C2,wi,bs,ot,Cout,up,rl) \
        hipLaunchKernelGGL((convm4_k<32,64,8,8,up>), dim3(4,32,8*((Cout)/32)), dim3(256), 0, stream, \
            (const uint4*)(i1), (C1)/8, (const uint4*)(i2), (C2)/8, WP(wi), bs, \
            (unsigned short*)(ot), Cout, rl, zp)
    #define CV2(i1,C1,i2,C2,wi,bs,ot,Cout,up,rl) \
        hipLaunchKernelGGL((convm4_k<64,32,8,7,up>), dim3(4,16,8*((Cout)/64)), dim3(256), 0, stream, \
            (const uint4*)(i1), (C1)/8, (const uint4*)(i2), (C2)/8, WP(wi), bs, \
            (unsigned short*)(ot), Cout, rl, zp)
    #define CV3(i1,C1,i2,C2,wi,bs,ot,Cout,up,rl) \
        hipLaunchKernelGGL((convm4_k<32,32,8,6,up>), dim3(2,8,8*((Cout)/32)), dim3(256), 0, stream, \
            (const uint4*)(i1), (C1)/8, (const uint4*)(i2), (C2)/8, WP(wi), bs, \
            (unsigned short*)(ot), Cout, rl, zp)

    // encoder
    hipLaunchKernelGGL(conv0_k, dim3(16, 16, 32), dim3(16, 16), 0, stream,
                       x, e1w1, e1b1, (unsigned short*)A);        // e1a -> A
    CV1(A, 32, nullptr, 0, 0, e1b2, Bb, 32, 0, 1);               // e1  -> B
    {
        int N = 8 * 128 * 128 * 4;
        hipLaunchKernelGGL(poolh_k, dim3((N + 255) / 256), dim3(256), 0, stream,
                           (const uint4*)Bb, (uint4*)C, 128, 128, 4, N);  // p1 -> C
    }
    CV2(C, 32, nullptr, 0, 1, e2b1, A, 64, 0, 1);                // e2a -> A
    CV2(A, 64, nullptr, 0, 2, e2b2, D, 64, 0, 1);                // e2  -> D
    {
        int N = 8 * 64 * 64 * 8;
        hipLaunchKernelGGL(poolh_k, dim3((N + 255) / 256), dim3(256), 0, stream,
                           (const uint4*)D, (uint4*)C, 64, 64, 8, N);     // p2 -> C
    }
    // bottleneck
    CV3(C, 64, nullptr, 0, 3, bb1, E, 128, 0, 1);                // b1 -> E
    CV3(E, 128, nullptr, 0, 4, bb2, A, 128, 0, 1);               // b2 -> A
    // decoder level 2
    CV2(A, 128, nullptr, 0, 5, u2b, E, 64, 1, 1);                // u2 -> E (upsample)
    CV2(E, 64, D, 64, 6, d2b1, A, 64, 0, 1);                     // d2a -> A (concat)
    CV2(A, 64, nullptr, 0, 7, d2b2, D, 64, 0, 1);                // d2 -> D
    // decoder level 1
    CV1(D, 64, nullptr, 0, 8, u1b, A, 32, 1, 1);                 // u1 -> A (upsample)
    CV1(A, 32, Bb, 32, 9, d1b1, D, 32, 0, 1);                    // d1a -> D+E (concat)
    CV1(D, 32, nullptr, 0, 10, d1b2, Bb, 32, 0, 1);              // d1 -> B
    // fused 1x1 conv (MFMA) + row scan -> ii rows
    hipLaunchKernelGGL(rowprep_k, dim3(256, 8), dim3(256), 0, stream,
                       (const uint4*)Bb, (const uint4*)fw16, fb, ii);
    // segmented column scan
    hipLaunchKernelGGL(colA_k, dim3(256, 3), dim3(256), 0, stream, ii, Sbuf);
    hipLaunchKernelGGL(colB_k, dim3(256, 4), dim3(256), 0, stream, ii, Sbuf);
    // ROI pool + FC
    hipLaunchKernelGGL(pool_k, dim3(8 * 1056 * 49 / 256), dim3(256), 0, stream,
                       ii, rois, pooled);
    hipLaunchKernelGGL(fc_k, dim3(66, 8), dim3(512), 0, stream,
                       pooled, fcwT, fcb, (float*)d_out);
    #undef CV1
    #undef CV2
    #undef CV3
}